// Round 1
// baseline (832.553 us; speedup 1.0000x reference)
//
#include <hip/hip_runtime.h>

// ---- problem constants (from setup_inputs) ----
#define HW    9216          // H*W = 96*96
#define NTOK  18432         // B*HW
#define NBATCH 2
#define KSPLIT_KEYS 4608    // HW/2 keys per split block

typedef float  floatx4 __attribute__((ext_vector_type(4)));
typedef short  short8  __attribute__((ext_vector_type(8)));

__device__ __forceinline__ unsigned short f2bf(float f) {
  unsigned int u = __float_as_uint(f);
  u += 0x7fffu + ((u >> 16) & 1u);          // round-to-nearest-even
  return (unsigned short)(u >> 16);
}

__device__ __forceinline__ float wave64_sum(float v) {
  #pragma unroll
  for (int d = 1; d < 64; d <<= 1) v += __shfl_xor(v, d);
  return v;
}

// ======================================================================
// Kernel 1: [B,C,HW] -> per-token LN1 -> h (fp32), q*0.125/k (bf16 [tok][c]),
//           v (bf16 transposed [c][tok]).  One wave per token.
// ======================================================================
__global__ __launch_bounds__(256) void k_qkv(
    const float* __restrict__ x,
    const float* __restrict__ wq, const float* __restrict__ bq,
    const float* __restrict__ wk, const float* __restrict__ bk,
    const float* __restrict__ wv, const float* __restrict__ bv,
    const float* __restrict__ g1, const float* __restrict__ b1,
    float* __restrict__ h_ws, unsigned short* __restrict__ qg,
    unsigned short* __restrict__ kg, unsigned short* __restrict__ vtg)
{
  __shared__ float hbuf[4][64];
  const int tid = threadIdx.x, wid = tid >> 6, c = tid & 63;
  const long t = (long)blockIdx.x * 4 + wid;
  const int b = (int)(t / HW), n = (int)(t % HW);

  const float val = x[((long)b * 64 + c) * HW + n];
  const float mu  = wave64_sum(val) * (1.f / 64.f);
  const float dv  = val - mu;
  const float var = wave64_sum(dv * dv) * (1.f / 64.f);
  const float hval = dv * rsqrtf(var + 1e-5f) * g1[c] + b1[c];

  h_ws[t * 64 + c] = hval;
  hbuf[wid][c] = hval;                      // wave-local, no barrier needed

  float aq = bq[c], ak = bk[c], av = bv[c];
  const float4* h4  = (const float4*)hbuf[wid];
  const float4* wq4 = (const float4*)(wq + c * 64);
  const float4* wk4 = (const float4*)(wk + c * 64);
  const float4* wv4 = (const float4*)(wv + c * 64);
  #pragma unroll
  for (int i = 0; i < 16; ++i) {
    const float4 hh = h4[i];
    float4 w = wq4[i];
    aq = fmaf(w.x,hh.x, fmaf(w.y,hh.y, fmaf(w.z,hh.z, fmaf(w.w,hh.w, aq))));
    w = wk4[i];
    ak = fmaf(w.x,hh.x, fmaf(w.y,hh.y, fmaf(w.z,hh.z, fmaf(w.w,hh.w, ak))));
    w = wv4[i];
    av = fmaf(w.x,hh.x, fmaf(w.y,hh.y, fmaf(w.z,hh.z, fmaf(w.w,hh.w, av))));
  }
  qg[t * 64 + c] = f2bf(aq * 0.125f);       // fold scale = C^-0.5 into Q
  kg[t * 64 + c] = f2bf(ak);
  vtg[((long)b * 64 + c) * HW + n] = f2bf(av);
}

// ======================================================================
// Kernel 2: flash attention, 16x16x32 bf16 MFMA.
// Grid (288, 2): x = b*144 + query-tile(64q), y = key-split (2x4608 keys).
// Block 256 = 4 waves x 16 queries. K/V staged to LDS in MFMA-frag order.
// Writes unnormalized O + (m,l) per split; kernel 3 merges.
// ======================================================================
__global__ __launch_bounds__(256) void k_attn(
    const unsigned short* __restrict__ qg, const unsigned short* __restrict__ kg,
    const unsigned short* __restrict__ vtg, const int* __restrict__ maskg,
    float* __restrict__ opart, float* __restrict__ mlpart)
{
  // frag-order tiles: slot*64 lanes * 8 bf16 (16B per lane-slot)
  __shared__ __align__(16) unsigned short kf_lds[8 * 64 * 8]; // [sub*2+s][lane][8]
  __shared__ __align__(16) unsigned short vf_lds[8 * 64 * 8]; // [k2*4+f][lane][8]
  __shared__ __align__(16) unsigned short pf_lds[4 * 64 * 8]; // [wid][lane][8]

  const int tid = threadIdx.x;
  const int wid = tid >> 6, lane = tid & 63;
  const int mcol = lane & 15, quad = lane >> 4;
  const int b  = blockIdx.x / 144;
  const int qt = blockIdx.x % 144;
  const int split = blockIdx.y;
  const int q0 = qt * 64 + wid * 16;
  const long tokq = (long)b * HW + q0;

  // Q A-frags (A[m=mcol][k=quad*8+j], k-steps s=0,1)
  const short8 qf0 = *(const short8*)(qg + (tokq + mcol) * 64 + quad * 8);
  const short8 qf1 = *(const short8*)(qg + (tokq + mcol) * 64 + 32 + quad * 8);

  floatx4 oa[4];
  #pragma unroll
  for (int f = 0; f < 4; ++f) oa[f] = (floatx4){0.f, 0.f, 0.f, 0.f};
  float mrow[4], lrow[4];
  #pragma unroll
  for (int r = 0; r < 4; ++r) { mrow[r] = -1e30f; lrow[r] = 0.f; }

  const int kroot = split * KSPLIT_KEYS;
  for (int kt = 0; kt < KSPLIT_KEYS / 64; ++kt) {
    const int kbase = kroot + kt * 64;
    __syncthreads();
    // ---- stage 64 keys of K and V into frag-order LDS (b128 in, b128 out) ----
    #pragma unroll
    for (int p = 0; p < 2; ++p) {
      const int idx = p * 256 + tid;
      {
        const int key = idx >> 3, c8 = idx & 7;
        const int sub = key >> 4, nn = key & 15, ss = c8 >> 2, qd = c8 & 3;
        *(short8*)(kf_lds + ((sub * 2 + ss) * 64 + qd * 16 + nn) * 8) =
            *(const short8*)(kg + ((long)b * HW + kbase + key) * 64 + c8 * 8);
      }
      {
        const int ch = idx >> 3, kc = idx & 7;
        const int k2 = kc >> 2, qd = kc & 3, ff = ch >> 4, nn = ch & 15;
        *(short8*)(vf_lds + ((k2 * 4 + ff) * 64 + qd * 16 + nn) * 8) =
            *(const short8*)(vtg + ((long)b * 64 + ch) * HW + kbase + kc * 8);
      }
    }
    __syncthreads();

    int msk[4];
    #pragma unroll
    for (int u = 0; u < 4; ++u) msk[u] = maskg[b * HW + kbase + u * 16 + mcol];

    #pragma unroll
    for (int k2 = 0; k2 < 2; ++k2) {
      // S = Q*K^T for 2 subtiles of 16 keys (kf slot = sub*2+s, sub = k2*2+u)
      const short8 kA0 = *(const short8*)(kf_lds + ((k2 * 4 + 0) * 64 + lane) * 8);
      const short8 kA1 = *(const short8*)(kf_lds + ((k2 * 4 + 1) * 64 + lane) * 8);
      const short8 kB0 = *(const short8*)(kf_lds + ((k2 * 4 + 2) * 64 + lane) * 8);
      const short8 kB1 = *(const short8*)(kf_lds + ((k2 * 4 + 3) * 64 + lane) * 8);
      floatx4 s0 = (floatx4){0.f,0.f,0.f,0.f}, s1 = (floatx4){0.f,0.f,0.f,0.f};
      s0 = __builtin_amdgcn_mfma_f32_16x16x32_bf16(qf0, kA0, s0, 0, 0, 0);
      s0 = __builtin_amdgcn_mfma_f32_16x16x32_bf16(qf1, kA1, s0, 0, 0, 0);
      s1 = __builtin_amdgcn_mfma_f32_16x16x32_bf16(qf0, kB0, s1, 0, 0, 0);
      s1 = __builtin_amdgcn_mfma_f32_16x16x32_bf16(qf1, kB1, s1, 0, 0, 0);

      const int v0 = msk[k2 * 2 + 0], v1 = msk[k2 * 2 + 1];
      float p0s[4], p1s[4];
      #pragma unroll
      for (int r = 0; r < 4; ++r) {
        // row-max over 16 lanes sharing this quad (keys at col=mcol)
        float a0 = v0 ? s0[r] : -1e30f;
        float a1 = v1 ? s1[r] : -1e30f;
        float mx = fmaxf(a0, a1);
        mx = fmaxf(mx, __shfl_xor(mx, 1));
        mx = fmaxf(mx, __shfl_xor(mx, 2));
        mx = fmaxf(mx, __shfl_xor(mx, 4));
        mx = fmaxf(mx, __shfl_xor(mx, 8));
        const float mnew  = fmaxf(mrow[r], mx);
        const float alpha = __expf(mrow[r] - mnew);
        const float p0 = v0 ? __expf(s0[r] - mnew) : 0.f;
        const float p1 = v1 ? __expf(s1[r] - mnew) : 0.f;
        float rs = p0 + p1;
        rs += __shfl_xor(rs, 1);
        rs += __shfl_xor(rs, 2);
        rs += __shfl_xor(rs, 4);
        rs += __shfl_xor(rs, 8);
        lrow[r] = lrow[r] * alpha + rs;
        mrow[r] = mnew;
        #pragma unroll
        for (int f = 0; f < 4; ++f) oa[f][r] *= alpha;
        p0s[r] = p0; p1s[r] = p1;
      }

      // P: D-layout -> A-layout via per-wave LDS round-trip
      const int jcol  = mcol & 7;
      const int l0b = ((mcol      ) >> 3) * 16 + quad * 4;   // sub u=0 target lane
      const int l1b = (((16 + mcol)) >> 3) * 16 + quad * 4;  // sub u=1 target lane
      #pragma unroll
      for (int r = 0; r < 4; ++r) {
        pf_lds[(wid * 64 + l0b + r) * 8 + jcol] = f2bf(p0s[r]);
        pf_lds[(wid * 64 + l1b + r) * 8 + jcol] = f2bf(p1s[r]);
      }
      const short8 pf = *(const short8*)(pf_lds + (wid * 64 + lane) * 8);
      #pragma unroll
      for (int f = 0; f < 4; ++f) {
        const short8 vf = *(const short8*)(vf_lds + ((k2 * 4 + f) * 64 + lane) * 8);
        oa[f] = __builtin_amdgcn_mfma_f32_16x16x32_bf16(pf, vf, oa[f], 0, 0, 0);
      }
    }
  }

  // epilogue: unnormalized O + (m,l) per split
  #pragma unroll
  for (int f = 0; f < 4; ++f) {
    #pragma unroll
    for (int r = 0; r < 4; ++r) {
      opart[((long)split * NTOK + tokq + quad * 4 + r) * 64 + f * 16 + mcol] = oa[f][r];
    }
  }
  if (mcol == 0) {
    #pragma unroll
    for (int r = 0; r < 4; ++r) {
      const long mi = (long)split * NTOK + tokq + quad * 4 + r;
      mlpart[mi * 2]     = mrow[r];
      mlpart[mi * 2 + 1] = lrow[r];
    }
  }
}

// ======================================================================
// Kernel 3: merge splits -> att; wo proj + residual; LN2; FFN(gelu exact);
// mask-zero; transposed coalesced store. One wave per token, 4 tokens/block.
// ======================================================================
__global__ __launch_bounds__(256) void k_post(
    const float* __restrict__ opart, const float* __restrict__ mlpart,
    const float* __restrict__ h_ws, const int* __restrict__ maskg,
    const float* __restrict__ wo, const float* __restrict__ bo,
    const float* __restrict__ g2, const float* __restrict__ b2,
    const float* __restrict__ w1, const float* __restrict__ bf1,
    const float* __restrict__ w2, const float* __restrict__ bf2,
    float* __restrict__ out)
{
  __shared__ float abuf[4][64];
  __shared__ float nbuf[4][64];
  __shared__ float gbuf[4][256];
  __shared__ float tbuf[64][5];   // +1 pad breaks bank conflicts on write

  const int tid = threadIdx.x, wid = tid >> 6, c = tid & 63;
  const long t = (long)blockIdx.x * 4 + wid;
  const int b = (int)(t / HW), n = (int)(t % HW);

  // merge the two key-splits (flash-decode combine)
  const float m0 = mlpart[t * 2],              l0 = mlpart[t * 2 + 1];
  const float m1 = mlpart[((long)NTOK + t) * 2], l1 = mlpart[((long)NTOK + t) * 2 + 1];
  const float M  = fmaxf(m0, m1);
  const float e0 = __expf(m0 - M), e1 = __expf(m1 - M);
  const float att = (opart[t * 64 + c] * e0 +
                     opart[(long)NTOK * 64 + t * 64 + c] * e1) / (l0 * e0 + l1 * e1);
  abuf[wid][c] = att;

  float acc = bo[c];
  {
    const float4* a4 = (const float4*)abuf[wid];
    const float4* w4 = (const float4*)(wo + c * 64);
    #pragma unroll
    for (int i = 0; i < 16; ++i) {
      const float4 av = a4[i], wv = w4[i];
      acc = fmaf(wv.x,av.x, fmaf(wv.y,av.y, fmaf(wv.z,av.z, fmaf(wv.w,av.w, acc))));
    }
  }
  const float h2  = h_ws[t * 64 + c] + acc;     // residual onto LN1 output
  const float mu  = wave64_sum(h2) * (1.f / 64.f);
  const float dv  = h2 - mu;
  const float var = wave64_sum(dv * dv) * (1.f / 64.f);
  const float hn  = dv * rsqrtf(var + 1e-5f) * g2[c] + b2[c];
  nbuf[wid][c] = hn;

  #pragma unroll
  for (int u4 = 0; u4 < 4; ++u4) {
    const int u = u4 * 64 + c;
    float a = bf1[u];
    const float4* n4  = (const float4*)nbuf[wid];
    const float4* w14 = (const float4*)(w1 + u * 64);
    #pragma unroll
    for (int i = 0; i < 16; ++i) {
      const float4 nv = n4[i], wv = w14[i];
      a = fmaf(wv.x,nv.x, fmaf(wv.y,nv.y, fmaf(wv.z,nv.z, fmaf(wv.w,nv.w, a))));
    }
    gbuf[wid][u] = 0.5f * a * (1.0f + erff(a * 0.70710678118654752f)); // exact gelu
  }

  float o = hn + bf2[c];                        // residual onto LN2 output
  {
    const float4* g4  = (const float4*)gbuf[wid];
    const float4* w24 = (const float4*)(w2 + c * 256);
    #pragma unroll 8
    for (int i = 0; i < 64; ++i) {
      const float4 gv = g4[i], wv = w24[i];
      o = fmaf(wv.x,gv.x, fmaf(wv.y,gv.y, fmaf(wv.z,gv.z, fmaf(wv.w,gv.w, o))));
    }
  }
  o = maskg[b * HW + n] ? o : 0.0f;

  tbuf[c][wid] = o;
  __syncthreads();
  if (wid == 0) {
    const int n0 = (int)(((long)blockIdx.x * 4) % HW);
    const float4 v = make_float4(tbuf[c][0], tbuf[c][1], tbuf[c][2], tbuf[c][3]);
    *(float4*)(out + ((long)b * 64 + c) * HW + n0) = v;
  }
}

// ======================================================================
extern "C" void kernel_launch(void* const* d_in, const int* in_sizes, int n_in,
                              void* d_out, int out_size, void* d_ws, size_t ws_size,
                              hipStream_t stream) {
  (void)in_sizes; (void)n_in; (void)out_size; (void)ws_size;
  const float* x   = (const float*)d_in[0];
  const int*   msk = (const int*)  d_in[1];
  const float* wq  = (const float*)d_in[2];
  const float* bq  = (const float*)d_in[3];
  const float* wk  = (const float*)d_in[4];
  const float* bk  = (const float*)d_in[5];
  const float* wv  = (const float*)d_in[6];
  const float* bv  = (const float*)d_in[7];
  const float* wo  = (const float*)d_in[8];
  const float* bo  = (const float*)d_in[9];
  const float* g1  = (const float*)d_in[10];
  const float* b1  = (const float*)d_in[11];
  const float* g2  = (const float*)d_in[12];
  const float* b2  = (const float*)d_in[13];
  const float* w1  = (const float*)d_in[14];
  const float* bf1 = (const float*)d_in[15];
  const float* w2  = (const float*)d_in[16];
  const float* bf2 = (const float*)d_in[17];
  float* out = (float*)d_out;

  // workspace layout (bytes), all 16B-aligned
  char* ws = (char*)d_ws;
  float*          h_ws   = (float*)(ws + 0);                 // 18432*64*4  = 4,718,592
  unsigned short* qg     = (unsigned short*)(ws + 4718592);  // 18432*64*2  = 2,359,296
  unsigned short* kg     = (unsigned short*)(ws + 7077888);  // 2,359,296
  unsigned short* vtg    = (unsigned short*)(ws + 9437184);  // 2,359,296  ([b][c][tok])
  float*          opart  = (float*)(ws + 11796480);          // 2*18432*64*4 = 9,437,184
  float*          mlpart = (float*)(ws + 21233664);          // 2*18432*2*4  = 294,912
  // total: 21,528,576 B

  k_qkv <<<dim3(4608),    dim3(256), 0, stream>>>(x, wq, bq, wk, bk, wv, bv, g1, b1,
                                                  h_ws, qg, kg, vtg);
  k_attn<<<dim3(288, 2),  dim3(256), 0, stream>>>(qg, kg, vtg, msk, opart, mlpart);
  k_post<<<dim3(4608),    dim3(256), 0, stream>>>(opart, mlpart, h_ws, msk,
                                                  wo, bo, g2, b2, w1, bf1, w2, bf2, out);
}

// Round 2
// 615.853 us; speedup vs baseline: 1.3519x; 1.3519x over previous
//
#include <hip/hip_runtime.h>

// ---- problem constants ----
#define HW     9216
#define NTOK   18432
#define SPLITS 8
#define KPB    (HW / SPLITS)     // 1152 keys per block
#define KPW    (KPB / 4)         // 288 keys per wave
#define KITERS (KPW / 32)        // 9 iterations of 32 keys

typedef float  floatx4 __attribute__((ext_vector_type(4)));
typedef short  short8  __attribute__((ext_vector_type(8)));
typedef int    int4v   __attribute__((ext_vector_type(4)));

__device__ __forceinline__ unsigned short f2bf(float f) {   // RNE
  unsigned int u = __float_as_uint(f);
  u += 0x7fffu + ((u >> 16) & 1u);
  return (unsigned short)(u >> 16);
}
__device__ __forceinline__ float bf2f(unsigned short s) {
  return __uint_as_float(((unsigned int)s) << 16);
}
// pack two non-negative floats to bf16x2, round-half-up (cheap, p in [0,~2])
__device__ __forceinline__ int pk2(float a, float b) {
  unsigned ua = __float_as_uint(a) + 0x8000u;
  unsigned ub = __float_as_uint(b) + 0x8000u;
  return (int)((ua >> 16) | (ub & 0xffff0000u));
}

// ======================================================================
// k_prep: zero O-accumulator & l, mask->float, weights->bf16.
// grid 4608x256 covers NTOK*64 = 1,179,648 exactly.
// ======================================================================
__global__ __launch_bounds__(256) void k_prep(
    const int* __restrict__ mask,
    const float* __restrict__ wo, const float* __restrict__ w1, const float* __restrict__ w2,
    float* __restrict__ Oacc, float* __restrict__ ltot, float* __restrict__ maskf,
    unsigned short* __restrict__ wobf, unsigned short* __restrict__ w1bf,
    unsigned short* __restrict__ w2bf)
{
  const int idx = blockIdx.x * 256 + threadIdx.x;
  Oacc[idx] = 0.f;
  if (idx < NTOK) { ltot[idx] = 0.f; maskf[idx] = mask[idx] ? 1.f : 0.f; }
  if (idx < 4096)  wobf[idx] = f2bf(wo[idx]);
  if (idx < 16384) { w1bf[idx] = f2bf(w1[idx]); w2bf[idx] = f2bf(w2[idx]); }
}

// ======================================================================
// k_qkv: LN1 + Q/K/V projections. Block = 32 tokens, wave = 8 tokens
// (weight rows loaded once per 8 tokens). Writes h (bf16), q*scale, k
// ([tok][c] bf16) and v transposed ([c][tok] bf16).
// ======================================================================
__global__ __launch_bounds__(256) void k_qkv(
    const float* __restrict__ x,
    const float* __restrict__ wq, const float* __restrict__ bq,
    const float* __restrict__ wk, const float* __restrict__ bk,
    const float* __restrict__ wv, const float* __restrict__ bv,
    const float* __restrict__ g1, const float* __restrict__ b1,
    unsigned short* __restrict__ h_bf, unsigned short* __restrict__ qg,
    unsigned short* __restrict__ kg, unsigned short* __restrict__ vtg)
{
  __shared__ float xt[64][33];   // stride 33 -> conflict-free column reads
  __shared__ float hb[32][64];   // broadcast-read rows

  const int tid = threadIdx.x, wid = tid >> 6, c = tid & 63;
  const int t0 = blockIdx.x * 32;
  const int b  = t0 / HW, n0 = t0 % HW;

  // coalesced x tile load: [64c][32tok]
  #pragma unroll
  for (int p = 0; p < 2; ++p) {
    const int idx = p * 256 + tid;
    const int cc = idx >> 3, t4 = (idx & 7) * 4;
    const floatx4 v = *(const floatx4*)(x + ((long)b * 64 + cc) * HW + n0 + t4);
    xt[cc][t4 + 0] = v[0]; xt[cc][t4 + 1] = v[1];
    xt[cc][t4 + 2] = v[2]; xt[cc][t4 + 3] = v[3];
  }
  __syncthreads();

  const float g1v = g1[c], b1v = b1[c];
  float aq[8], ak[8], av[8];
  const float bqv = bq[c], bkv = bk[c], bvv = bv[c];

  #pragma unroll
  for (int tt = 0; tt < 8; ++tt) {
    const int tok = wid * 8 + tt;
    const float val = xt[c][tok];
    float s = val, q = val * val;
    #pragma unroll
    for (int d = 1; d < 64; d <<= 1) { s += __shfl_xor(s, d); q += __shfl_xor(q, d); }
    const float mu  = s * (1.f / 64.f);
    const float var = q * (1.f / 64.f) - mu * mu;
    const float hv  = (val - mu) * rsqrtf(var + 1e-5f) * g1v + b1v;
    hb[tok][c] = hv;
    h_bf[(long)(t0 + tok) * 64 + c] = f2bf(hv);
    aq[tt] = bqv; ak[tt] = bkv; av[tt] = bvv;
  }

  const floatx4* wq4 = (const floatx4*)(wq + c * 64);
  const floatx4* wk4 = (const floatx4*)(wk + c * 64);
  const floatx4* wv4 = (const floatx4*)(wv + c * 64);
  #pragma unroll
  for (int i = 0; i < 16; ++i) {
    const floatx4 wqv = wq4[i], wkv = wk4[i], wvv = wv4[i];
    #pragma unroll
    for (int tt = 0; tt < 8; ++tt) {
      const floatx4 hh = *(const floatx4*)&hb[wid * 8 + tt][i * 4];
      aq[tt] = fmaf(wqv[0],hh[0], fmaf(wqv[1],hh[1], fmaf(wqv[2],hh[2], fmaf(wqv[3],hh[3], aq[tt]))));
      ak[tt] = fmaf(wkv[0],hh[0], fmaf(wkv[1],hh[1], fmaf(wkv[2],hh[2], fmaf(wkv[3],hh[3], ak[tt]))));
      av[tt] = fmaf(wvv[0],hh[0], fmaf(wvv[1],hh[1], fmaf(wvv[2],hh[2], fmaf(wvv[3],hh[3], av[tt]))));
    }
  }

  #pragma unroll
  for (int tt = 0; tt < 8; ++tt) {
    const int tok = wid * 8 + tt;
    const long t = t0 + tok;
    qg[t * 64 + c] = f2bf(aq[tt] * 0.125f);      // fold C^-0.5
    kg[t * 64 + c] = f2bf(ak[tt]);
    vtg[((long)b * 64 + c) * HW + n0 + tok] = f2bf(av[tt]);
  }
}

// ======================================================================
// k_attn: flash attention without online max (|scores| << 80, fp32 exp is
// safe; masked keys multiply p by 0 -> identical to softmax with -1e9).
// S^T = mfma(K_frag, Q_frag): softmax state per-lane, no shuffles in loop.
// P^T D-layout -> B-layout via 8 in-register shuffles. K/V frags direct
// from global (L2-resident). Block: 4 waves x 288 keys, 64 shared queries;
// merge in LDS, atomicAdd into global O/l accumulators.
// ======================================================================
__global__ __launch_bounds__(256, 2) void k_attn(
    const unsigned short* __restrict__ qg, const unsigned short* __restrict__ kg,
    const unsigned short* __restrict__ vtg, const float* __restrict__ maskf,
    float* __restrict__ Oacc, float* __restrict__ ltot)
{
  __shared__ float otile[64 * 68];
  __shared__ float lbuf[4][64];

  const int tid = threadIdx.x, wid = tid >> 6, lane = tid & 63;
  const int mcol = lane & 15, quad = lane >> 4;
  const int b = blockIdx.x / 144, qt = blockIdx.x % 144, split = blockIdx.y;
  const long t0q = (long)b * HW + qt * 64;

  // Q fragments: B-layout (lane&15 = query, holds 8 channels)
  short8 qf[4][2];
  #pragma unroll
  for (int g = 0; g < 4; ++g)
    #pragma unroll
    for (int s = 0; s < 2; ++s)
      qf[g][s] = *(const short8*)(qg + (t0q + g * 16 + mcol) * 64 + s * 32 + quad * 8);

  floatx4 oT[4][4];
  #pragma unroll
  for (int g = 0; g < 4; ++g)
    #pragma unroll
    for (int f = 0; f < 4; ++f) oT[g][f] = (floatx4){0.f,0.f,0.f,0.f};
  float lsum[4] = {0.f, 0.f, 0.f, 0.f};

  const unsigned short* kgb = kg  + (long)b * HW * 64;
  const unsigned short* vb  = vtg + (long)b * 64 * HW;
  const float* mfb = maskf + (long)b * HW;
  const int kstart = split * KPB + wid * KPW;
  const int slane  = ((lane & 16) << 1) + mcol;
  const bool hi    = (lane & 32) != 0;

  // prefetch iteration 0
  short8 kA[2][2], vA[4];
  floatx4 mf0, mf1;
  {
    const int kb = kstart;
    #pragma unroll
    for (int sub = 0; sub < 2; ++sub)
      #pragma unroll
      for (int ss = 0; ss < 2; ++ss)
        kA[sub][ss] = *(const short8*)(kgb + (long)(kb + sub * 16 + mcol) * 64 + ss * 32 + quad * 8);
    #pragma unroll
    for (int f = 0; f < 4; ++f)
      vA[f] = *(const short8*)(vb + (long)(f * 16 + mcol) * HW + kb + quad * 8);
    mf0 = *(const floatx4*)(mfb + kb + quad * 4);
    mf1 = *(const floatx4*)(mfb + kb + 16 + quad * 4);
  }

  for (int it = 0; it < KITERS; ++it) {
    short8 kA2[2][2], vA2[4];
    floatx4 mf0n, mf1n;
    if (it + 1 < KITERS) {
      const int kb = kstart + (it + 1) * 32;
      #pragma unroll
      for (int sub = 0; sub < 2; ++sub)
        #pragma unroll
        for (int ss = 0; ss < 2; ++ss)
          kA2[sub][ss] = *(const short8*)(kgb + (long)(kb + sub * 16 + mcol) * 64 + ss * 32 + quad * 8);
      #pragma unroll
      for (int f = 0; f < 4; ++f)
        vA2[f] = *(const short8*)(vb + (long)(f * 16 + mcol) * HW + kb + quad * 8);
      mf0n = *(const floatx4*)(mfb + kb + quad * 4);
      mf1n = *(const floatx4*)(mfb + kb + 16 + quad * 4);
    }

    #pragma unroll
    for (int g = 0; g < 4; ++g) {
      floatx4 s0 = (floatx4){0.f,0.f,0.f,0.f}, s1 = (floatx4){0.f,0.f,0.f,0.f};
      s0 = __builtin_amdgcn_mfma_f32_16x16x32_bf16(kA[0][0], qf[g][0], s0, 0, 0, 0);
      s0 = __builtin_amdgcn_mfma_f32_16x16x32_bf16(kA[0][1], qf[g][1], s0, 0, 0, 0);
      s1 = __builtin_amdgcn_mfma_f32_16x16x32_bf16(kA[1][0], qf[g][0], s1, 0, 0, 0);
      s1 = __builtin_amdgcn_mfma_f32_16x16x32_bf16(kA[1][1], qf[g][1], s1, 0, 0, 0);

      float p0[4], p1[4];
      #pragma unroll
      for (int r = 0; r < 4; ++r) {
        p0[r] = __expf(s0[r]) * mf0[r];
        p1[r] = __expf(s1[r]) * mf1[r];
      }
      lsum[g] += ((p0[0]+p0[1])+(p0[2]+p0[3])) + ((p1[0]+p1[1])+(p1[2]+p1[3]));

      // P^T: D-layout -> B-layout, in-register (quad-only permutation)
      const int u001 = pk2(p0[0], p0[1]), u023 = pk2(p0[2], p0[3]);
      const int u101 = pk2(p1[0], p1[1]), u123 = pk2(p1[2], p1[3]);
      const int a0 = __shfl(u001, slane),      b0 = __shfl(u101, slane);
      const int a1 = __shfl(u023, slane),      b1 = __shfl(u123, slane);
      const int a2 = __shfl(u001, slane + 16), b2 = __shfl(u101, slane + 16);
      const int a3 = __shfl(u023, slane + 16), b3 = __shfl(u123, slane + 16);
      int4v pv;
      pv[0] = hi ? b0 : a0; pv[1] = hi ? b1 : a1;
      pv[2] = hi ? b2 : a2; pv[3] = hi ? b3 : a3;
      const short8 pf = __builtin_bit_cast(short8, pv);

      #pragma unroll
      for (int f = 0; f < 4; ++f)
        oT[g][f] = __builtin_amdgcn_mfma_f32_16x16x32_bf16(vA[f], pf, oT[g][f], 0, 0, 0);
    }

    #pragma unroll
    for (int sub = 0; sub < 2; ++sub)
      #pragma unroll
      for (int ss = 0; ss < 2; ++ss) kA[sub][ss] = kA2[sub][ss];
    #pragma unroll
    for (int f = 0; f < 4; ++f) vA[f] = vA2[f];
    mf0 = mf0n; mf1 = mf1n;
  }

  // l: reduce across quads (16-stride lanes)
  #pragma unroll
  for (int g = 0; g < 4; ++g) {
    float v = lsum[g];
    v += __shfl_xor(v, 16); v += __shfl_xor(v, 32);
    lsum[g] = v;
  }
  if (lane < 16) {
    #pragma unroll
    for (int g = 0; g < 4; ++g) lbuf[wid][g * 16 + lane] = lsum[g];
  }

  // merge 4 waves' O tiles in LDS (serialized adds)
  for (int w = 0; w < 4; ++w) {
    if (wid == w) {
      #pragma unroll
      for (int g = 0; g < 4; ++g)
        #pragma unroll
        for (int f = 0; f < 4; ++f)
          #pragma unroll
          for (int r = 0; r < 4; ++r) {
            const int a = (g * 16 + mcol) * 68 + f * 16 + quad * 4 + r;
            if (w == 0) otile[a] = oT[g][f][r]; else otile[a] += oT[g][f][r];
          }
    }
    __syncthreads();
  }

  // push to global accumulators (splits are additive: no max state)
  const int row = tid >> 2, c16 = (tid & 3) * 16;
  #pragma unroll
  for (int i = 0; i < 16; ++i)
    unsafeAtomicAdd(&Oacc[(t0q + row) * 64 + c16 + i], otile[row * 68 + c16 + i]);
  if (tid < 64)
    unsafeAtomicAdd(&ltot[t0q + tid],
                    ((lbuf[0][tid] + lbuf[1][tid]) + (lbuf[2][tid] + lbuf[3][tid])));
}

// ======================================================================
// k_post: att = O/l; wo-GEMM + residual; LN2; w1-GEMM + exact GELU;
// w2-GEMM + residual; mask; transposed coalesced store.
// Block = 32 tokens, all GEMMs bf16 MFMA, LN/residuals fp32.
// ======================================================================
__global__ __launch_bounds__(256) void k_post(
    const float* __restrict__ Oacc, const float* __restrict__ ltot,
    const unsigned short* __restrict__ h_bf, const float* __restrict__ maskf,
    const unsigned short* __restrict__ wobf, const float* __restrict__ bo,
    const float* __restrict__ g2, const float* __restrict__ b2,
    const unsigned short* __restrict__ w1bf, const float* __restrict__ bf1,
    const unsigned short* __restrict__ w2bf, const float* __restrict__ bf2,
    float* __restrict__ out)
{
  __shared__ float          h2_lds[32 * 68];
  __shared__ unsigned short att_lds[32 * 72];
  __shared__ unsigned short hn_lds[32 * 72];
  __shared__ unsigned short g_lds[32 * 264];
  __shared__ float          ot_lds[32 * 68];
  __shared__ float          linv[32];
  __shared__ float          st_mu[32], st_rs[32];

  const int tid = threadIdx.x, wid = tid >> 6, lane = tid & 63;
  const int mcol = lane & 15, quad = lane >> 4;
  const int t0 = blockIdx.x * 32;
  const int b = t0 / HW, n0 = t0 % HW;

  if (tid < 32) linv[tid] = 1.0f / ltot[t0 + tid];

  // phase 1: att (bf16) and h2 prefill (h + bo)
  const int tok = tid >> 3, c8 = (tid & 7) * 8;
  floatx4 o0 = *(const floatx4*)(Oacc + (long)(t0 + tok) * 64 + c8);
  floatx4 o1 = *(const floatx4*)(Oacc + (long)(t0 + tok) * 64 + c8 + 4);
  const short8 hb8 = *(const short8*)(h_bf + (long)(t0 + tok) * 64 + c8);
  const floatx4 bo0 = *(const floatx4*)(bo + c8);
  const floatx4 bo1 = *(const floatx4*)(bo + c8 + 4);
  __syncthreads();
  {
    const float sc = linv[tok];
    int4v av;
    av[0] = pk2(o0[0]*sc, o0[1]*sc); av[1] = pk2(o0[2]*sc, o0[3]*sc);
    av[2] = pk2(o1[0]*sc, o1[1]*sc); av[3] = pk2(o1[2]*sc, o1[3]*sc);
    *(int4v*)(att_lds + tok * 72 + c8) = av;
    floatx4 h20, h21;
    #pragma unroll
    for (int i = 0; i < 4; ++i) {
      h20[i] = bf2f((unsigned short)hb8[i])     + bo0[i];
      h21[i] = bf2f((unsigned short)hb8[i + 4]) + bo1[i];
    }
    *(floatx4*)(h2_lds + tok * 68 + c8)     = h20;
    *(floatx4*)(h2_lds + tok * 68 + c8 + 4) = h21;
  }
  __syncthreads();

  // phase 2: wo-GEMM, D added into h2_lds
  const int Mt = wid & 1, nbase = (wid >> 1) * 2;
  {
    const short8 aA0 = *(const short8*)(att_lds + (Mt * 16 + mcol) * 72 + quad * 8);
    const short8 aA1 = *(const short8*)(att_lds + (Mt * 16 + mcol) * 72 + 32 + quad * 8);
    #pragma unroll
    for (int nt = 0; nt < 2; ++nt) {
      const int nc = (nbase + nt) * 16;
      const short8 b0 = *(const short8*)(wobf + (nc + mcol) * 64 + quad * 8);
      const short8 b1 = *(const short8*)(wobf + (nc + mcol) * 64 + 32 + quad * 8);
      floatx4 d = (floatx4){0.f,0.f,0.f,0.f};
      d = __builtin_amdgcn_mfma_f32_16x16x32_bf16(aA0, b0, d, 0, 0, 0);
      d = __builtin_amdgcn_mfma_f32_16x16x32_bf16(aA1, b1, d, 0, 0, 0);
      #pragma unroll
      for (int r = 0; r < 4; ++r)
        h2_lds[(Mt * 16 + quad * 4 + r) * 68 + nc + mcol] += d[r];
    }
  }
  __syncthreads();

  // phase 3: LN2 stats
  {
    floatx4 v0 = *(const floatx4*)(h2_lds + tok * 68 + c8);
    floatx4 v1 = *(const floatx4*)(h2_lds + tok * 68 + c8 + 4);
    float s1 = (v0[0]+v0[1])+(v0[2]+v0[3]) + (v1[0]+v1[1])+(v1[2]+v1[3]);
    float s2 = (v0[0]*v0[0]+v0[1]*v0[1])+(v0[2]*v0[2]+v0[3]*v0[3])
             + (v1[0]*v1[0]+v1[1]*v1[1])+(v1[2]*v1[2]+v1[3]*v1[3]);
    #pragma unroll
    for (int d = 1; d < 8; d <<= 1) { s1 += __shfl_xor(s1, d); s2 += __shfl_xor(s2, d); }
    if ((tid & 7) == 0) {
      const float mu = s1 * (1.f / 64.f);
      const float var = s2 * (1.f / 64.f) - mu * mu;
      st_mu[tok] = mu; st_rs[tok] = rsqrtf(var + 1e-5f);
    }
  }
  __syncthreads();

  // phase 4: hn (bf16) for w1-GEMM
  {
    const float mu = st_mu[tok], rs = st_rs[tok];
    const floatx4 v0 = *(const floatx4*)(h2_lds + tok * 68 + c8);
    const floatx4 v1 = *(const floatx4*)(h2_lds + tok * 68 + c8 + 4);
    const floatx4 ga = *(const floatx4*)(g2 + c8), gb = *(const floatx4*)(g2 + c8 + 4);
    const floatx4 ba = *(const floatx4*)(b2 + c8), bb = *(const floatx4*)(b2 + c8 + 4);
    float hn[8];
    #pragma unroll
    for (int i = 0; i < 4; ++i) {
      hn[i]     = (v0[i] - mu) * rs * ga[i] + ba[i];
      hn[i + 4] = (v1[i] - mu) * rs * gb[i] + bb[i];
    }
    int4v hv;
    hv[0] = pk2(hn[0], hn[1]); hv[1] = pk2(hn[2], hn[3]);   // note: pk2 round-half-up; hn can be negative but
    hv[2] = pk2(hn[4], hn[5]); hv[3] = pk2(hn[6], hn[7]);   // +0x8000 rounding works for any sign (magnitude RNAway)
    *(int4v*)(hn_lds + tok * 72 + c8) = hv;
  }
  __syncthreads();

  // phase 5: w1-GEMM + exact GELU -> g_lds (bf16)
  {
    const short8 aA0 = *(const short8*)(hn_lds + (Mt * 16 + mcol) * 72 + quad * 8);
    const short8 aA1 = *(const short8*)(hn_lds + (Mt * 16 + mcol) * 72 + 32 + quad * 8);
    #pragma unroll
    for (int nt = 0; nt < 8; ++nt) {
      const int u0 = ((wid >> 1) * 8 + nt) * 16;
      const short8 b0 = *(const short8*)(w1bf + (u0 + mcol) * 64 + quad * 8);
      const short8 b1 = *(const short8*)(w1bf + (u0 + mcol) * 64 + 32 + quad * 8);
      floatx4 d = (floatx4){0.f,0.f,0.f,0.f};
      d = __builtin_amdgcn_mfma_f32_16x16x32_bf16(aA0, b0, d, 0, 0, 0);
      d = __builtin_amdgcn_mfma_f32_16x16x32_bf16(aA1, b1, d, 0, 0, 0);
      const float bf1v = bf1[u0 + mcol];
      #pragma unroll
      for (int r = 0; r < 4; ++r) {
        const float a = d[r] + bf1v;
        const float gl = 0.5f * a * (1.0f + erff(a * 0.70710678118654752f));
        g_lds[(Mt * 16 + quad * 4 + r) * 264 + u0 + mcol] = f2bf(gl);
      }
    }
  }
  __syncthreads();

  // phase 6: w2-GEMM + residual + mask -> ot_lds
  {
    floatx4 acc[2];
    acc[0] = (floatx4){0.f,0.f,0.f,0.f}; acc[1] = (floatx4){0.f,0.f,0.f,0.f};
    #pragma unroll
    for (int ks = 0; ks < 8; ++ks) {
      const short8 aA = *(const short8*)(g_lds + (Mt * 16 + mcol) * 264 + ks * 32 + quad * 8);
      #pragma unroll
      for (int nt = 0; nt < 2; ++nt) {
        const int nc = (nbase + nt) * 16;
        const short8 bB = *(const short8*)(w2bf + (nc + mcol) * 256 + ks * 32 + quad * 8);
        acc[nt] = __builtin_amdgcn_mfma_f32_16x16x32_bf16(aA, bB, acc[nt], 0, 0, 0);
      }
    }
    #pragma unroll
    for (int nt = 0; nt < 2; ++nt) {
      const int cc = (nbase + nt) * 16 + mcol;
      const float g2v = g2[cc], b2v = b2[cc], bf2v = bf2[cc];
      #pragma unroll
      for (int r = 0; r < 4; ++r) {
        const int tokr = Mt * 16 + quad * 4 + r;
        const float hn = (h2_lds[tokr * 68 + cc] - st_mu[tokr]) * st_rs[tokr] * g2v + b2v;
        const float o  = (hn + acc[nt][r] + bf2v) * maskf[t0 + tokr];
        ot_lds[tokr * 68 + cc] = o;
      }
    }
  }
  __syncthreads();

  // transposed coalesced store: out[b][c][n]
  {
    const int c = tid >> 2, tg = (tid & 3) * 8;
    floatx4 v0, v1;
    #pragma unroll
    for (int i = 0; i < 4; ++i) {
      v0[i] = ot_lds[(tg + i) * 68 + c];
      v1[i] = ot_lds[(tg + 4 + i) * 68 + c];
    }
    float* dst = out + ((long)b * 64 + c) * HW + n0 + tg;
    *(floatx4*)dst = v0;
    *(floatx4*)(dst + 4) = v1;
  }
}

// ======================================================================
extern "C" void kernel_launch(void* const* d_in, const int* in_sizes, int n_in,
                              void* d_out, int out_size, void* d_ws, size_t ws_size,
                              hipStream_t stream) {
  (void)in_sizes; (void)n_in; (void)out_size; (void)ws_size;
  const float* x   = (const float*)d_in[0];
  const int*   msk = (const int*)  d_in[1];
  const float* wq  = (const float*)d_in[2];
  const float* bq  = (const float*)d_in[3];
  const float* wk  = (const float*)d_in[4];
  const float* bk  = (const float*)d_in[5];
  const float* wv  = (const float*)d_in[6];
  const float* bv  = (const float*)d_in[7];
  const float* wo  = (const float*)d_in[8];
  const float* bo  = (const float*)d_in[9];
  const float* g1  = (const float*)d_in[10];
  const float* b1  = (const float*)d_in[11];
  const float* g2  = (const float*)d_in[12];
  const float* b2  = (const float*)d_in[13];
  const float* w1  = (const float*)d_in[14];
  const float* bf1 = (const float*)d_in[15];
  const float* w2  = (const float*)d_in[16];
  const float* bf2 = (const float*)d_in[17];
  float* out = (float*)d_out;

  // workspace layout (bytes), all 16B-aligned; total 14,376,960
  char* ws = (char*)d_ws;
  unsigned short* h_bf  = (unsigned short*)(ws + 0);         // NTOK*64*2 = 2,359,296
  unsigned short* qg    = (unsigned short*)(ws + 2359296);
  unsigned short* kg    = (unsigned short*)(ws + 4718592);
  unsigned short* vtg   = (unsigned short*)(ws + 7077888);
  float*          Oacc  = (float*)(ws + 9437184);            // NTOK*64*4 = 4,718,592
  float*          ltot  = (float*)(ws + 14155776);           // 73,728
  float*          maskf = (float*)(ws + 14229504);           // 73,728
  unsigned short* wobf  = (unsigned short*)(ws + 14303232);  // 8,192
  unsigned short* w1bf  = (unsigned short*)(ws + 14311424);  // 32,768
  unsigned short* w2bf  = (unsigned short*)(ws + 14344192);  // 32,768

  k_prep<<<dim3(4608),     dim3(256), 0, stream>>>(msk, wo, w1, w2, Oacc, ltot, maskf,
                                                   wobf, w1bf, w2bf);
  k_qkv <<<dim3(576),      dim3(256), 0, stream>>>(x, wq, bq, wk, bk, wv, bv, g1, b1,
                                                   h_bf, qg, kg, vtg);
  k_attn<<<dim3(288, SPLITS), dim3(256), 0, stream>>>(qg, kg, vtg, maskf, Oacc, ltot);
  k_post<<<dim3(576),      dim3(256), 0, stream>>>(Oacc, ltot, h_bf, maskf,
                                                   wobf, bo, g2, b2, w1bf, bf1, w2bf, bf2, out);
}

// Round 3
// 323.623 us; speedup vs baseline: 2.5726x; 1.9030x over previous
//
#include <hip/hip_runtime.h>

// ---- problem constants ----
#define HW     9216
#define NTOK   18432
#define SPLITS 4
#define KPB    (HW / SPLITS)     // 2304 keys per split
#define KPW    (KPB / 4)         // 576 keys per wave
#define KITERS (KPW / 32)        // 18 iterations of 32 keys

typedef float  floatx4 __attribute__((ext_vector_type(4)));
typedef short  short8  __attribute__((ext_vector_type(8)));
typedef int    int4v   __attribute__((ext_vector_type(4)));

__device__ __forceinline__ unsigned short f2bf(float f) {   // RNE
  unsigned int u = __float_as_uint(f);
  u += 0x7fffu + ((u >> 16) & 1u);
  return (unsigned short)(u >> 16);
}
__device__ __forceinline__ float bf2f(unsigned short s) {
  return __uint_as_float(((unsigned int)s) << 16);
}
// pack two floats to bf16x2 (round-half-away; works for either sign)
__device__ __forceinline__ int pk2(float a, float b) {
  unsigned ua = __float_as_uint(a) + 0x8000u;
  unsigned ub = __float_as_uint(b) + 0x8000u;
  return (int)((ua >> 16) | (ub & 0xffff0000u));
}

// ======================================================================
// k_qkv: LN1 + Q/K/V projections (wave = 8 tokens). Also folds in the
// one-time prep: mask->float and wo/w1/w2 -> bf16 (first 144 blocks).
// ======================================================================
__global__ __launch_bounds__(256) void k_qkv(
    const float* __restrict__ x,
    const float* __restrict__ wq, const float* __restrict__ bq,
    const float* __restrict__ wk, const float* __restrict__ bk,
    const float* __restrict__ wv, const float* __restrict__ bv,
    const float* __restrict__ g1, const float* __restrict__ b1,
    const int* __restrict__ mask,
    const float* __restrict__ wo, const float* __restrict__ w1,
    const float* __restrict__ w2,
    unsigned short* __restrict__ h_bf, unsigned short* __restrict__ qg,
    unsigned short* __restrict__ kg, unsigned short* __restrict__ vtg,
    float* __restrict__ maskf, unsigned short* __restrict__ wobf,
    unsigned short* __restrict__ w1bf, unsigned short* __restrict__ w2bf)
{
  __shared__ float xt[64][33];
  __shared__ float hb[32][64];

  const int tid = threadIdx.x, wid = tid >> 6, c = tid & 63;
  const int bx = blockIdx.x;
  const int t0 = bx * 32;
  const int b  = t0 / HW, n0 = t0 % HW;

  // ---- folded prep (independent of main work) ----
  if (tid < 32) maskf[t0 + tid] = mask[t0 + tid] ? 1.f : 0.f;
  if (bx < 16)       { const int i = bx * 256 + tid;        wobf[i] = f2bf(wo[i]); }
  else if (bx < 80)  { const int i = (bx - 16) * 256 + tid; w1bf[i] = f2bf(w1[i]); }
  else if (bx < 144) { const int i = (bx - 80) * 256 + tid; w2bf[i] = f2bf(w2[i]); }

  // coalesced x tile load: [64c][32tok]
  #pragma unroll
  for (int p = 0; p < 2; ++p) {
    const int idx = p * 256 + tid;
    const int cc = idx >> 3, t4 = (idx & 7) * 4;
    const floatx4 v = *(const floatx4*)(x + ((long)b * 64 + cc) * HW + n0 + t4);
    xt[cc][t4 + 0] = v[0]; xt[cc][t4 + 1] = v[1];
    xt[cc][t4 + 2] = v[2]; xt[cc][t4 + 3] = v[3];
  }
  __syncthreads();

  const float g1v = g1[c], b1v = b1[c];
  float aq[8], ak[8], av[8];
  const float bqv = bq[c], bkv = bk[c], bvv = bv[c];

  #pragma unroll
  for (int tt = 0; tt < 8; ++tt) {
    const int tok = wid * 8 + tt;
    const float val = xt[c][tok];
    float s = val, q = val * val;
    #pragma unroll
    for (int d = 1; d < 64; d <<= 1) { s += __shfl_xor(s, d); q += __shfl_xor(q, d); }
    const float mu  = s * (1.f / 64.f);
    const float var = q * (1.f / 64.f) - mu * mu;
    const float hv  = (val - mu) * rsqrtf(var + 1e-5f) * g1v + b1v;
    hb[tok][c] = hv;
    h_bf[(long)(t0 + tok) * 64 + c] = f2bf(hv);
    aq[tt] = bqv; ak[tt] = bkv; av[tt] = bvv;
  }

  const floatx4* wq4 = (const floatx4*)(wq + c * 64);
  const floatx4* wk4 = (const floatx4*)(wk + c * 64);
  const floatx4* wv4 = (const floatx4*)(wv + c * 64);
  #pragma unroll
  for (int i = 0; i < 16; ++i) {
    const floatx4 wqv = wq4[i], wkv = wk4[i], wvv = wv4[i];
    #pragma unroll
    for (int tt = 0; tt < 8; ++tt) {
      const floatx4 hh = *(const floatx4*)&hb[wid * 8 + tt][i * 4];
      aq[tt] = fmaf(wqv[0],hh[0], fmaf(wqv[1],hh[1], fmaf(wqv[2],hh[2], fmaf(wqv[3],hh[3], aq[tt]))));
      ak[tt] = fmaf(wkv[0],hh[0], fmaf(wkv[1],hh[1], fmaf(wkv[2],hh[2], fmaf(wkv[3],hh[3], ak[tt]))));
      av[tt] = fmaf(wvv[0],hh[0], fmaf(wvv[1],hh[1], fmaf(wvv[2],hh[2], fmaf(wvv[3],hh[3], av[tt]))));
    }
  }

  #pragma unroll
  for (int tt = 0; tt < 8; ++tt) {
    const int tok = wid * 8 + tt;
    const long t = t0 + tok;
    qg[t * 64 + c] = f2bf(aq[tt] * 0.125f);      // fold C^-0.5
    kg[t * 64 + c] = f2bf(ak[tt]);
    vtg[((long)b * 64 + c) * HW + n0 + tok] = f2bf(av[tt]);
  }
}

// ======================================================================
// k_attn: flash attention without online max (|scores| << 80; masked keys
// get p=0 -> identical to softmax with -1e9). S^T = mfma(K,Q): per-lane
// softmax state, no shuffles for stats. P^T D->B layout via 8 in-register
// shuffles. K/V frags direct from global (L2-resident via XCD pinning:
// split = bx&3 matches round-robin block->XCD, so each XCD streams only
// its own K/V slice). Block merge via ds_add_f32; plain coalesced bf16
// partial stores (NO global atomics -- round-2's 295 MB write bomb).
// ======================================================================
__global__ __launch_bounds__(256, 2) void k_attn(
    const unsigned short* __restrict__ qg, const unsigned short* __restrict__ kg,
    const unsigned short* __restrict__ vtg, const float* __restrict__ maskf,
    unsigned short* __restrict__ opart, float* __restrict__ lpart)
{
  __shared__ float otile[64 * 68];
  __shared__ float lbuf[4][64];

  const int tid = threadIdx.x, wid = tid >> 6, lane = tid & 63;
  const int mcol = lane & 15, quad = lane >> 4;
  const int bx = blockIdx.x;
  const int split = bx & 3;            // XCD-pinned key split
  const int qidx  = bx >> 2;           // 0..287
  const int b = qidx / 144, qt = qidx % 144;
  const long t0q = (long)b * HW + qt * 64;

  // zero the block O-accumulator tile (64 x 68 = 4352 = 256*17 words)
  #pragma unroll
  for (int i = 0; i < 17; ++i) otile[tid + 256 * i] = 0.f;

  // Q fragments: B-layout (lane&15 = query, holds 8 channels)
  short8 qf[4][2];
  #pragma unroll
  for (int g = 0; g < 4; ++g)
    #pragma unroll
    for (int s = 0; s < 2; ++s)
      qf[g][s] = *(const short8*)(qg + (t0q + g * 16 + mcol) * 64 + s * 32 + quad * 8);

  floatx4 oT[4][4];
  #pragma unroll
  for (int g = 0; g < 4; ++g)
    #pragma unroll
    for (int f = 0; f < 4; ++f) oT[g][f] = (floatx4){0.f,0.f,0.f,0.f};
  float lsum[4] = {0.f, 0.f, 0.f, 0.f};

  const unsigned short* kgb = kg  + (long)b * HW * 64;
  const unsigned short* vb  = vtg + (long)b * 64 * HW;
  const float* mfb = maskf + (long)b * HW;
  const int kstart = split * KPB + wid * KPW;
  const int slane  = ((lane & 16) << 1) + mcol;
  const bool hi    = (lane & 32) != 0;

  // prefetch iteration 0
  short8 kA[2][2], vA[4];
  floatx4 mf0, mf1;
  {
    const int kb = kstart;
    #pragma unroll
    for (int sub = 0; sub < 2; ++sub)
      #pragma unroll
      for (int ss = 0; ss < 2; ++ss)
        kA[sub][ss] = *(const short8*)(kgb + (long)(kb + sub * 16 + mcol) * 64 + ss * 32 + quad * 8);
    #pragma unroll
    for (int f = 0; f < 4; ++f)
      vA[f] = *(const short8*)(vb + (long)(f * 16 + mcol) * HW + kb + quad * 8);
    mf0 = *(const floatx4*)(mfb + kb + quad * 4);
    mf1 = *(const floatx4*)(mfb + kb + 16 + quad * 4);
  }

  for (int it = 0; it < KITERS; ++it) {
    short8 kA2[2][2], vA2[4];
    floatx4 mf0n, mf1n;
    if (it + 1 < KITERS) {
      const int kb = kstart + (it + 1) * 32;
      #pragma unroll
      for (int sub = 0; sub < 2; ++sub)
        #pragma unroll
        for (int ss = 0; ss < 2; ++ss)
          kA2[sub][ss] = *(const short8*)(kgb + (long)(kb + sub * 16 + mcol) * 64 + ss * 32 + quad * 8);
      #pragma unroll
      for (int f = 0; f < 4; ++f)
        vA2[f] = *(const short8*)(vb + (long)(f * 16 + mcol) * HW + kb + quad * 8);
      mf0n = *(const floatx4*)(mfb + kb + quad * 4);
      mf1n = *(const floatx4*)(mfb + kb + 16 + quad * 4);
    }

    #pragma unroll
    for (int g = 0; g < 4; ++g) {
      floatx4 s0 = (floatx4){0.f,0.f,0.f,0.f}, s1 = (floatx4){0.f,0.f,0.f,0.f};
      s0 = __builtin_amdgcn_mfma_f32_16x16x32_bf16(kA[0][0], qf[g][0], s0, 0, 0, 0);
      s0 = __builtin_amdgcn_mfma_f32_16x16x32_bf16(kA[0][1], qf[g][1], s0, 0, 0, 0);
      s1 = __builtin_amdgcn_mfma_f32_16x16x32_bf16(kA[1][0], qf[g][0], s1, 0, 0, 0);
      s1 = __builtin_amdgcn_mfma_f32_16x16x32_bf16(kA[1][1], qf[g][1], s1, 0, 0, 0);

      float p0[4], p1[4];
      #pragma unroll
      for (int r = 0; r < 4; ++r) {
        p0[r] = __expf(s0[r]) * mf0[r];
        p1[r] = __expf(s1[r]) * mf1[r];
      }
      lsum[g] += ((p0[0]+p0[1])+(p0[2]+p0[3])) + ((p1[0]+p1[1])+(p1[2]+p1[3]));

      // P^T: D-layout -> B-layout, in-register (quad-only permutation)
      const int u001 = pk2(p0[0], p0[1]), u023 = pk2(p0[2], p0[3]);
      const int u101 = pk2(p1[0], p1[1]), u123 = pk2(p1[2], p1[3]);
      const int a0 = __shfl(u001, slane),      b0 = __shfl(u101, slane);
      const int a1 = __shfl(u023, slane),      b1 = __shfl(u123, slane);
      const int a2 = __shfl(u001, slane + 16), b2 = __shfl(u101, slane + 16);
      const int a3 = __shfl(u023, slane + 16), b3 = __shfl(u123, slane + 16);
      int4v pv;
      pv[0] = hi ? b0 : a0; pv[1] = hi ? b1 : a1;
      pv[2] = hi ? b2 : a2; pv[3] = hi ? b3 : a3;
      const short8 pf = __builtin_bit_cast(short8, pv);

      #pragma unroll
      for (int f = 0; f < 4; ++f)
        oT[g][f] = __builtin_amdgcn_mfma_f32_16x16x32_bf16(vA[f], pf, oT[g][f], 0, 0, 0);
    }

    #pragma unroll
    for (int sub = 0; sub < 2; ++sub)
      #pragma unroll
      for (int ss = 0; ss < 2; ++ss) kA[sub][ss] = kA2[sub][ss];
    #pragma unroll
    for (int f = 0; f < 4; ++f) vA[f] = vA2[f];
    mf0 = mf0n; mf1 = mf1n;
  }

  // l: reduce across quads (16-stride lanes)
  #pragma unroll
  for (int g = 0; g < 4; ++g) {
    float v = lsum[g];
    v += __shfl_xor(v, 16); v += __shfl_xor(v, 32);
    lsum[g] = v;
  }
  if (lane < 16) {
    #pragma unroll
    for (int g = 0; g < 4; ++g) lbuf[wid][g * 16 + lane] = lsum[g];
  }

  __syncthreads();   // otile zero-init + lbuf visible to all

  // merge 4 waves' O tiles via LDS float atomics (ds_add_f32, no return)
  #pragma unroll
  for (int g = 0; g < 4; ++g)
    #pragma unroll
    for (int f = 0; f < 4; ++f)
      #pragma unroll
      for (int r = 0; r < 4; ++r)
        atomicAdd(&otile[(g * 16 + mcol) * 68 + f * 16 + quad * 4 + r], oT[g][f][r]);
  __syncthreads();

  // coalesced bf16 partial store
  {
    const int row = tid >> 2, c16 = (tid & 3) * 16;
    const float* src = otile + row * 68 + c16;
    unsigned short* dst = opart + ((long)split * NTOK + t0q + row) * 64 + c16;
    int4v pa, pb;
    pa[0] = pk2(src[0],  src[1]);  pa[1] = pk2(src[2],  src[3]);
    pa[2] = pk2(src[4],  src[5]);  pa[3] = pk2(src[6],  src[7]);
    pb[0] = pk2(src[8],  src[9]);  pb[1] = pk2(src[10], src[11]);
    pb[2] = pk2(src[12], src[13]); pb[3] = pk2(src[14], src[15]);
    *(int4v*)dst = pa;
    *(int4v*)(dst + 8) = pb;
  }
  if (tid < 64)
    lpart[(long)split * NTOK + t0q + tid] =
        (lbuf[0][tid] + lbuf[1][tid]) + (lbuf[2][tid] + lbuf[3][tid]);
}

// ======================================================================
// k_post: merge split partials -> att; wo-GEMM + residual; LN2; w1-GEMM
// + exact GELU; w2-GEMM + residual; mask; transposed coalesced store.
// ======================================================================
__global__ __launch_bounds__(256) void k_post(
    const unsigned short* __restrict__ opart, const float* __restrict__ lpart,
    const unsigned short* __restrict__ h_bf, const float* __restrict__ maskf,
    const unsigned short* __restrict__ wobf, const float* __restrict__ bo,
    const float* __restrict__ g2, const float* __restrict__ b2,
    const unsigned short* __restrict__ w1bf, const float* __restrict__ bf1,
    const unsigned short* __restrict__ w2bf, const float* __restrict__ bf2,
    float* __restrict__ out)
{
  __shared__ float          h2_lds[32 * 68];
  __shared__ unsigned short att_lds[32 * 72];
  __shared__ unsigned short hn_lds[32 * 72];
  __shared__ unsigned short g_lds[32 * 264];
  __shared__ float          ot_lds[32 * 68];
  __shared__ float          linv[32];
  __shared__ float          st_mu[32], st_rs[32];

  const int tid = threadIdx.x, wid = tid >> 6, lane = tid & 63;
  const int mcol = lane & 15, quad = lane >> 4;
  const int t0 = blockIdx.x * 32;
  const int b = t0 / HW, n0 = t0 % HW;

  if (tid < 32) {
    float l = 0.f;
    #pragma unroll
    for (int s = 0; s < SPLITS; ++s) l += lpart[(long)s * NTOK + t0 + tid];
    linv[tid] = 1.0f / l;
  }

  // phase 1: merge O partials, att (bf16) and h2 prefill (h + bo)
  const int tok = tid >> 3, c8 = (tid & 7) * 8;
  float o[8];
  #pragma unroll
  for (int i = 0; i < 8; ++i) o[i] = 0.f;
  #pragma unroll
  for (int s = 0; s < SPLITS; ++s) {
    const short8 op = *(const short8*)(opart + ((long)s * NTOK + t0 + tok) * 64 + c8);
    #pragma unroll
    for (int i = 0; i < 8; ++i) o[i] += bf2f((unsigned short)op[i]);
  }
  const short8 hb8 = *(const short8*)(h_bf + (long)(t0 + tok) * 64 + c8);
  const floatx4 bo0 = *(const floatx4*)(bo + c8);
  const floatx4 bo1 = *(const floatx4*)(bo + c8 + 4);
  __syncthreads();
  {
    const float sc = linv[tok];
    int4v av;
    av[0] = pk2(o[0]*sc, o[1]*sc); av[1] = pk2(o[2]*sc, o[3]*sc);
    av[2] = pk2(o[4]*sc, o[5]*sc); av[3] = pk2(o[6]*sc, o[7]*sc);
    *(int4v*)(att_lds + tok * 72 + c8) = av;
    floatx4 h20, h21;
    #pragma unroll
    for (int i = 0; i < 4; ++i) {
      h20[i] = bf2f((unsigned short)hb8[i])     + bo0[i];
      h21[i] = bf2f((unsigned short)hb8[i + 4]) + bo1[i];
    }
    *(floatx4*)(h2_lds + tok * 68 + c8)     = h20;
    *(floatx4*)(h2_lds + tok * 68 + c8 + 4) = h21;
  }
  __syncthreads();

  // phase 2: wo-GEMM, D added into h2_lds
  const int Mt = wid & 1, nbase = (wid >> 1) * 2;
  {
    const short8 aA0 = *(const short8*)(att_lds + (Mt * 16 + mcol) * 72 + quad * 8);
    const short8 aA1 = *(const short8*)(att_lds + (Mt * 16 + mcol) * 72 + 32 + quad * 8);
    #pragma unroll
    for (int nt = 0; nt < 2; ++nt) {
      const int nc = (nbase + nt) * 16;
      const short8 b0 = *(const short8*)(wobf + (nc + mcol) * 64 + quad * 8);
      const short8 b1 = *(const short8*)(wobf + (nc + mcol) * 64 + 32 + quad * 8);
      floatx4 d = (floatx4){0.f,0.f,0.f,0.f};
      d = __builtin_amdgcn_mfma_f32_16x16x32_bf16(aA0, b0, d, 0, 0, 0);
      d = __builtin_amdgcn_mfma_f32_16x16x32_bf16(aA1, b1, d, 0, 0, 0);
      #pragma unroll
      for (int r = 0; r < 4; ++r)
        h2_lds[(Mt * 16 + quad * 4 + r) * 68 + nc + mcol] += d[r];
    }
  }
  __syncthreads();

  // phase 3: LN2 stats
  {
    floatx4 v0 = *(const floatx4*)(h2_lds + tok * 68 + c8);
    floatx4 v1 = *(const floatx4*)(h2_lds + tok * 68 + c8 + 4);
    float s1 = (v0[0]+v0[1])+(v0[2]+v0[3]) + (v1[0]+v1[1])+(v1[2]+v1[3]);
    float s2 = (v0[0]*v0[0]+v0[1]*v0[1])+(v0[2]*v0[2]+v0[3]*v0[3])
             + (v1[0]*v1[0]+v1[1]*v1[1])+(v1[2]*v1[2]+v1[3]*v1[3]);
    #pragma unroll
    for (int d = 1; d < 8; d <<= 1) { s1 += __shfl_xor(s1, d); s2 += __shfl_xor(s2, d); }
    if ((tid & 7) == 0) {
      const float mu = s1 * (1.f / 64.f);
      const float var = s2 * (1.f / 64.f) - mu * mu;
      st_mu[tok] = mu; st_rs[tok] = rsqrtf(var + 1e-5f);
    }
  }
  __syncthreads();

  // phase 4: hn (bf16) for w1-GEMM
  {
    const float mu = st_mu[tok], rs = st_rs[tok];
    const floatx4 v0 = *(const floatx4*)(h2_lds + tok * 68 + c8);
    const floatx4 v1 = *(const floatx4*)(h2_lds + tok * 68 + c8 + 4);
    const floatx4 ga = *(const floatx4*)(g2 + c8), gb = *(const floatx4*)(g2 + c8 + 4);
    const floatx4 ba = *(const floatx4*)(b2 + c8), bb = *(const floatx4*)(b2 + c8 + 4);
    float hn[8];
    #pragma unroll
    for (int i = 0; i < 4; ++i) {
      hn[i]     = (v0[i] - mu) * rs * ga[i] + ba[i];
      hn[i + 4] = (v1[i] - mu) * rs * gb[i] + bb[i];
    }
    int4v hv;
    hv[0] = pk2(hn[0], hn[1]); hv[1] = pk2(hn[2], hn[3]);
    hv[2] = pk2(hn[4], hn[5]); hv[3] = pk2(hn[6], hn[7]);
    *(int4v*)(hn_lds + tok * 72 + c8) = hv;
  }
  __syncthreads();

  // phase 5: w1-GEMM + exact GELU -> g_lds (bf16)
  {
    const short8 aA0 = *(const short8*)(hn_lds + (Mt * 16 + mcol) * 72 + quad * 8);
    const short8 aA1 = *(const short8*)(hn_lds + (Mt * 16 + mcol) * 72 + 32 + quad * 8);
    #pragma unroll
    for (int nt = 0; nt < 8; ++nt) {
      const int u0 = ((wid >> 1) * 8 + nt) * 16;
      const short8 b0 = *(const short8*)(w1bf + (u0 + mcol) * 64 + quad * 8);
      const short8 b1 = *(const short8*)(w1bf + (u0 + mcol) * 64 + 32 + quad * 8);
      floatx4 d = (floatx4){0.f,0.f,0.f,0.f};
      d = __builtin_amdgcn_mfma_f32_16x16x32_bf16(aA0, b0, d, 0, 0, 0);
      d = __builtin_amdgcn_mfma_f32_16x16x32_bf16(aA1, b1, d, 0, 0, 0);
      const float bf1v = bf1[u0 + mcol];
      #pragma unroll
      for (int r = 0; r < 4; ++r) {
        const float a = d[r] + bf1v;
        const float gl = 0.5f * a * (1.0f + erff(a * 0.70710678118654752f));
        g_lds[(Mt * 16 + quad * 4 + r) * 264 + u0 + mcol] = f2bf(gl);
      }
    }
  }
  __syncthreads();

  // phase 6: w2-GEMM + residual + mask -> ot_lds
  {
    floatx4 acc[2];
    acc[0] = (floatx4){0.f,0.f,0.f,0.f}; acc[1] = (floatx4){0.f,0.f,0.f,0.f};
    #pragma unroll
    for (int ks = 0; ks < 8; ++ks) {
      const short8 aA = *(const short8*)(g_lds + (Mt * 16 + mcol) * 264 + ks * 32 + quad * 8);
      #pragma unroll
      for (int nt = 0; nt < 2; ++nt) {
        const int nc = (nbase + nt) * 16;
        const short8 bB = *(const short8*)(w2bf + (nc + mcol) * 256 + ks * 32 + quad * 8);
        acc[nt] = __builtin_amdgcn_mfma_f32_16x16x32_bf16(aA, bB, acc[nt], 0, 0, 0);
      }
    }
    #pragma unroll
    for (int nt = 0; nt < 2; ++nt) {
      const int cc = (nbase + nt) * 16 + mcol;
      const float g2v = g2[cc], b2v = b2[cc], bf2v = bf2[cc];
      #pragma unroll
      for (int r = 0; r < 4; ++r) {
        const int tokr = Mt * 16 + quad * 4 + r;
        const float hn = (h2_lds[tokr * 68 + cc] - st_mu[tokr]) * st_rs[tokr] * g2v + b2v;
        const float o  = (hn + acc[nt][r] + bf2v) * maskf[t0 + tokr];
        ot_lds[tokr * 68 + cc] = o;
      }
    }
  }
  __syncthreads();

  // transposed coalesced store: out[b][c][n]
  {
    const int c = tid >> 2, tg = (tid & 3) * 8;
    floatx4 v0, v1;
    #pragma unroll
    for (int i = 0; i < 4; ++i) {
      v0[i] = ot_lds[(tg + i) * 68 + c];
      v1[i] = ot_lds[(tg + 4 + i) * 68 + c];
    }
    float* dst = out + ((long)b * 64 + c) * HW + n0 + tg;
    *(floatx4*)dst = v0;
    *(floatx4*)(dst + 4) = v1;
  }
}

// ======================================================================
extern "C" void kernel_launch(void* const* d_in, const int* in_sizes, int n_in,
                              void* d_out, int out_size, void* d_ws, size_t ws_size,
                              hipStream_t stream) {
  (void)in_sizes; (void)n_in; (void)out_size; (void)ws_size;
  const float* x   = (const float*)d_in[0];
  const int*   msk = (const int*)  d_in[1];
  const float* wq  = (const float*)d_in[2];
  const float* bq  = (const float*)d_in[3];
  const float* wk  = (const float*)d_in[4];
  const float* bk  = (const float*)d_in[5];
  const float* wv  = (const float*)d_in[6];
  const float* bv  = (const float*)d_in[7];
  const float* wo  = (const float*)d_in[8];
  const float* bo  = (const float*)d_in[9];
  const float* g1  = (const float*)d_in[10];
  const float* b1  = (const float*)d_in[11];
  const float* g2  = (const float*)d_in[12];
  const float* b2  = (const float*)d_in[13];
  const float* w1  = (const float*)d_in[14];
  const float* bf1 = (const float*)d_in[15];
  const float* w2  = (const float*)d_in[16];
  const float* bf2 = (const float*)d_in[17];
  float* out = (float*)d_out;

  // workspace layout (bytes), all 16B-aligned; total 19,316,736
  char* ws = (char*)d_ws;
  unsigned short* h_bf  = (unsigned short*)(ws + 0);          // 2,359,296
  unsigned short* qg    = (unsigned short*)(ws + 2359296);    // 2,359,296
  unsigned short* kg    = (unsigned short*)(ws + 4718592);    // 2,359,296
  unsigned short* vtg   = (unsigned short*)(ws + 7077888);    // 2,359,296
  unsigned short* opart = (unsigned short*)(ws + 9437184);    // SPLITS*NTOK*64*2 = 9,437,184
  float*          lpart = (float*)(ws + 18874368);            // SPLITS*NTOK*4 = 294,912
  float*          maskf = (float*)(ws + 19169280);            // 73,728
  unsigned short* wobf  = (unsigned short*)(ws + 19243008);   // 8,192
  unsigned short* w1bf  = (unsigned short*)(ws + 19251200);   // 32,768
  unsigned short* w2bf  = (unsigned short*)(ws + 19283968);   // 32,768

  k_qkv <<<dim3(576),          dim3(256), 0, stream>>>(
      x, wq, bq, wk, bk, wv, bv, g1, b1, msk, wo, w1, w2,
      h_bf, qg, kg, vtg, maskf, wobf, w1bf, w2bf);
  k_attn<<<dim3(288 * SPLITS), dim3(256), 0, stream>>>(qg, kg, vtg, maskf, opart, lpart);
  k_post<<<dim3(576),          dim3(256), 0, stream>>>(
      opart, lpart, h_bf, maskf, wobf, bo, g2, b2, w1bf, bf1, w2bf, bf2, out);
}

// Round 5
// 198.589 us; speedup vs baseline: 4.1923x; 1.6296x over previous
//
#include <hip/hip_runtime.h>

// ---- problem constants ----
#define HW     9216
#define NTOK   18432
#define SPLITS 8
#define KPB    (HW / SPLITS)     // 1152 keys per split
#define KIT    (KPB / 32)        // 36 tiles of 32 keys
#define QT     192               // queries per attn block (4 waves x 48)

typedef float  floatx4 __attribute__((ext_vector_type(4)));
typedef short  short8  __attribute__((ext_vector_type(8)));
typedef int    int4v   __attribute__((ext_vector_type(4)));

__device__ __forceinline__ unsigned short f2bf(float f) {   // RNE
  unsigned int u = __float_as_uint(f);
  u += 0x7fffu + ((u >> 16) & 1u);
  return (unsigned short)(u >> 16);
}
__device__ __forceinline__ float bf2f(unsigned short s) {
  return __uint_as_float(((unsigned int)s) << 16);
}
// pack two floats to bf16x2 (round-half-away)
__device__ __forceinline__ int pk2(float a, float b) {
  unsigned ua = __float_as_uint(a) + 0x8000u;
  unsigned ub = __float_as_uint(b) + 0x8000u;
  return (int)((ua >> 16) | (ub & 0xffff0000u));
}

// ======================================================================
// k_qkv: LN1 + Q/K/V projections (wave = 8 tokens). Q stays [tok][c];
// K and V are written PRE-SWIZZLED into MFMA fragment-tile order (one
// 32-key tile per block, via LDS transpose -> coalesced 16B writes), so
// k_attn staging is a pure contiguous copy. Also folds one-time prep
// (mask->float, wo/w1/w2 -> bf16).
//
// ksw tile layout: [b*288+tile][slot=sub*2+ss][lane=quad*16+m][8]
//   element = K[tile*32 + sub*16 + m][ss*32 + quad*8 + j]
// vsw tile layout: [b*288+tile][f][lane=quad*16+m][8]
//   element = V[c = f*16 + m][key = tile*32 + quad*8 + j]
// ======================================================================
__global__ __launch_bounds__(256) void k_qkv(
    const float* __restrict__ x,
    const float* __restrict__ wq, const float* __restrict__ bq,
    const float* __restrict__ wk, const float* __restrict__ bk,
    const float* __restrict__ wv, const float* __restrict__ bv,
    const float* __restrict__ g1, const float* __restrict__ b1,
    const int* __restrict__ mask,
    const float* __restrict__ wo, const float* __restrict__ w1,
    const float* __restrict__ w2,
    unsigned short* __restrict__ h_bf, unsigned short* __restrict__ qg,
    unsigned short* __restrict__ ksw, unsigned short* __restrict__ vsw,
    float* __restrict__ maskf, unsigned short* __restrict__ wobf,
    unsigned short* __restrict__ w1bf, unsigned short* __restrict__ w2bf)
{
  __shared__ float xt[64][33];
  __shared__ float hb[32][64];
  __shared__ unsigned short kt[32][72];   // [tok][c], padded row
  __shared__ unsigned short vt[64][40];   // [c][tok], padded row

  const int tid = threadIdx.x, wid = tid >> 6, c = tid & 63;
  const int bx = blockIdx.x;
  const int t0 = bx * 32;
  const int b  = t0 / HW, n0 = t0 % HW;

  // ---- folded one-time prep ----
  if (tid < 32) maskf[t0 + tid] = mask[t0 + tid] ? 1.f : 0.f;
  if (bx < 16)       { const int i = bx * 256 + tid;        wobf[i] = f2bf(wo[i]); }
  else if (bx < 80)  { const int i = (bx - 16) * 256 + tid; w1bf[i] = f2bf(w1[i]); }
  else if (bx < 144) { const int i = (bx - 80) * 256 + tid; w2bf[i] = f2bf(w2[i]); }

  // coalesced x tile load: [64c][32tok]
  #pragma unroll
  for (int p = 0; p < 2; ++p) {
    const int idx = p * 256 + tid;
    const int cc = idx >> 3, t4 = (idx & 7) * 4;
    const floatx4 v = *(const floatx4*)(x + ((long)b * 64 + cc) * HW + n0 + t4);
    xt[cc][t4 + 0] = v[0]; xt[cc][t4 + 1] = v[1];
    xt[cc][t4 + 2] = v[2]; xt[cc][t4 + 3] = v[3];
  }
  __syncthreads();

  const float g1v = g1[c], b1v = b1[c];
  float aq[8], ak[8], av[8];
  const float bqv = bq[c], bkv = bk[c], bvv = bv[c];

  #pragma unroll
  for (int tt = 0; tt < 8; ++tt) {
    const int tok = wid * 8 + tt;
    const float val = xt[c][tok];
    float s = val, q = val * val;
    #pragma unroll
    for (int d = 1; d < 64; d <<= 1) { s += __shfl_xor(s, d); q += __shfl_xor(q, d); }
    const float mu  = s * (1.f / 64.f);
    const float var = q * (1.f / 64.f) - mu * mu;
    const float hv  = (val - mu) * rsqrtf(var + 1e-5f) * g1v + b1v;
    hb[tok][c] = hv;
    h_bf[(long)(t0 + tok) * 64 + c] = f2bf(hv);
    aq[tt] = bqv; ak[tt] = bkv; av[tt] = bvv;
  }

  const floatx4* wq4 = (const floatx4*)(wq + c * 64);
  const floatx4* wk4 = (const floatx4*)(wk + c * 64);
  const floatx4* wv4 = (const floatx4*)(wv + c * 64);
  #pragma unroll
  for (int i = 0; i < 16; ++i) {
    const floatx4 wqv = wq4[i], wkv = wk4[i], wvv = wv4[i];
    #pragma unroll
    for (int tt = 0; tt < 8; ++tt) {
      const floatx4 hh = *(const floatx4*)&hb[wid * 8 + tt][i * 4];
      aq[tt] = fmaf(wqv[0],hh[0], fmaf(wqv[1],hh[1], fmaf(wqv[2],hh[2], fmaf(wqv[3],hh[3], aq[tt]))));
      ak[tt] = fmaf(wkv[0],hh[0], fmaf(wkv[1],hh[1], fmaf(wkv[2],hh[2], fmaf(wkv[3],hh[3], ak[tt]))));
      av[tt] = fmaf(wvv[0],hh[0], fmaf(wvv[1],hh[1], fmaf(wvv[2],hh[2], fmaf(wvv[3],hh[3], av[tt]))));
    }
  }

  #pragma unroll
  for (int tt = 0; tt < 8; ++tt) {
    const int tok = wid * 8 + tt;
    qg[(long)(t0 + tok) * 64 + c] = f2bf(aq[tt] * 0.125f);  // fold C^-0.5
    kt[tok][c] = f2bf(ak[tt]);
    vt[c][tok] = f2bf(av[tt]);
  }
  __syncthreads();

  // swizzled coalesced tile writes (block == one 32-key tile)
  const long tile = (long)b * 288 + (n0 >> 5);
  {
    const int slot = tid >> 6, l = tid & 63;
    const int m = l & 15, qd = l >> 4, sub = slot >> 1, ss = slot & 1;
    const short8 v8 = *(const short8*)(&kt[sub * 16 + m][ss * 32 + qd * 8]);
    *(short8*)(ksw + tile * 2048 + tid * 8) = v8;
  }
  {
    const int f = tid >> 6, l = tid & 63;
    const int m = l & 15, qd = l >> 4;
    const short8 v8 = *(const short8*)(&vt[f * 16 + m][qd * 8]);
    *(short8*)(vsw + tile * 2048 + tid * 8) = v8;
  }
}

// ======================================================================
// k_attn: flash attention, no online max (|scores| << 80; masked keys get
// p=0). S^T = mfma(K,Q): per-lane softmax state. P^T D->B layout via 8
// in-register shuffles. K/V double-buffered in LDS (frag order, staged as
// one contiguous 4KB copy each), shared by all 4 waves; waves own disjoint
// 48-query ranges -> no cross-wave merge. Grid 768 = 96 qblocks x 8 splits
// = exactly 3 blocks/CU; split = bx&7 pins each split to one XCD's L2.
// NOTE: double-buffer addresses computed arithmetically (NOT a pointer
// array -- LDS pointer arrays force an addrspacecast static initializer
// that gfx950 codegen rejects).
// ======================================================================
__global__ __launch_bounds__(256, 3) void k_attn(
    const unsigned short* __restrict__ qg, const unsigned short* __restrict__ ksw,
    const unsigned short* __restrict__ vsw, const float* __restrict__ maskf,
    unsigned short* __restrict__ opart, float* __restrict__ lpart)
{
  // layout: [0,4096) K buf0 | [4096,8192) V buf0 | [8192,12288) K buf1 |
  //         [12288,16384) V buf1 | [16384,20992) mask tile.
  // Epilogue overlays [0..17408) as per-wave fp32 transpose scratch.
  __shared__ __align__(16) char smem[20992];

  const int tid = threadIdx.x, wid = tid >> 6, lane = tid & 63;
  const int mcol = lane & 15, quad = lane >> 4;
  const int bx = blockIdx.x;
  const int split = bx & 7, qidx = bx >> 3;          // qidx 0..95
  const int b = qidx / 48, qt = qidx % 48;
  const long t0q = (long)b * HW + qt * QT + wid * 48;

  const unsigned short* kswt = ksw + ((long)b * 288 + split * KIT) * 2048;
  const unsigned short* vswt = vsw + ((long)b * 288 + split * KIT) * 2048;
  float* mtile = (float*)(smem + 16384);   // KPB floats

  // mask slice for this split -> LDS (one time)
  for (int i = tid; i < KPB; i += 256) mtile[i] = maskf[b * HW + split * KPB + i];

  // Q fragments: B-layout (lane&15 = query, holds 8 channels)
  short8 qf[3][2];
  #pragma unroll
  for (int g = 0; g < 3; ++g)
    #pragma unroll
    for (int s = 0; s < 2; ++s)
      qf[g][s] = *(const short8*)(qg + (t0q + g * 16 + mcol) * 64 + s * 32 + quad * 8);

  floatx4 oT[3][4];
  #pragma unroll
  for (int g = 0; g < 3; ++g)
    #pragma unroll
    for (int f = 0; f < 4; ++f) oT[g][f] = (floatx4){0.f,0.f,0.f,0.f};
  float lsum[3] = {0.f, 0.f, 0.f};

  const int slane = ((lane & 16) << 1) + mcol;
  const bool hi   = (lane & 32) != 0;

  // stage tile 0
  short8 kr = *(const short8*)(kswt + tid * 8);
  short8 vr = *(const short8*)(vswt + tid * 8);
  *(short8*)((unsigned short*)smem + tid * 8) = kr;
  *(short8*)((unsigned short*)(smem + 4096) + tid * 8) = vr;
  __syncthreads();

  for (int it = 0; it < KIT; ++it) {
    const int off = (it & 1) * 8192;
    const unsigned short* kfc = (const unsigned short*)(smem + off);
    const unsigned short* vfc = (const unsigned short*)(smem + off + 4096);
    if (it + 1 < KIT) {    // issue next-tile loads early; vmcnt lands after compute
      kr = *(const short8*)(kswt + (it + 1) * 2048 + tid * 8);
      vr = *(const short8*)(vswt + (it + 1) * 2048 + tid * 8);
    }

    // K fragments for this tile (shared by all 3 q-groups)
    const short8 kA00 = *(const short8*)(kfc + (0 * 64 + lane) * 8);
    const short8 kA01 = *(const short8*)(kfc + (1 * 64 + lane) * 8);
    const short8 kA10 = *(const short8*)(kfc + (2 * 64 + lane) * 8);
    const short8 kA11 = *(const short8*)(kfc + (3 * 64 + lane) * 8);
    const floatx4 mf0 = *(const floatx4*)(mtile + it * 32 + quad * 4);
    const floatx4 mf1 = *(const floatx4*)(mtile + it * 32 + 16 + quad * 4);

    short8 pf[3];
    #pragma unroll
    for (int g = 0; g < 3; ++g) {
      floatx4 s0 = (floatx4){0.f,0.f,0.f,0.f}, s1 = (floatx4){0.f,0.f,0.f,0.f};
      s0 = __builtin_amdgcn_mfma_f32_16x16x32_bf16(kA00, qf[g][0], s0, 0, 0, 0);
      s0 = __builtin_amdgcn_mfma_f32_16x16x32_bf16(kA01, qf[g][1], s0, 0, 0, 0);
      s1 = __builtin_amdgcn_mfma_f32_16x16x32_bf16(kA10, qf[g][0], s1, 0, 0, 0);
      s1 = __builtin_amdgcn_mfma_f32_16x16x32_bf16(kA11, qf[g][1], s1, 0, 0, 0);

      float p0[4], p1[4];
      #pragma unroll
      for (int r = 0; r < 4; ++r) {
        p0[r] = __expf(s0[r]) * mf0[r];
        p1[r] = __expf(s1[r]) * mf1[r];
      }
      lsum[g] += ((p0[0]+p0[1])+(p0[2]+p0[3])) + ((p1[0]+p1[1])+(p1[2]+p1[3]));

      // P^T: D-layout -> B-layout, in-register
      const int u001 = pk2(p0[0], p0[1]), u023 = pk2(p0[2], p0[3]);
      const int u101 = pk2(p1[0], p1[1]), u123 = pk2(p1[2], p1[3]);
      const int a0 = __shfl(u001, slane),      b0 = __shfl(u101, slane);
      const int a1 = __shfl(u023, slane),      b1 = __shfl(u123, slane);
      const int a2 = __shfl(u001, slane + 16), b2 = __shfl(u101, slane + 16);
      const int a3 = __shfl(u023, slane + 16), b3 = __shfl(u123, slane + 16);
      int4v pv;
      pv[0] = hi ? b0 : a0; pv[1] = hi ? b1 : a1;
      pv[2] = hi ? b2 : a2; pv[3] = hi ? b3 : a3;
      pf[g] = __builtin_bit_cast(short8, pv);
    }

    #pragma unroll
    for (int f = 0; f < 4; ++f) {
      const short8 vA = *(const short8*)(vfc + (f * 64 + lane) * 8);
      #pragma unroll
      for (int g = 0; g < 3; ++g)
        oT[g][f] = __builtin_amdgcn_mfma_f32_16x16x32_bf16(vA, pf[g], oT[g][f], 0, 0, 0);
    }

    if (it + 1 < KIT) {
      unsigned short* kfn = (unsigned short*)(smem + (off ^ 8192));
      unsigned short* vfn = (unsigned short*)(smem + (off ^ 8192) + 4096);
      *(short8*)(kfn + tid * 8) = kr;
      *(short8*)(vfn + tid * 8) = vr;
    }
    __syncthreads();
  }

  // epilogue: per-wave fp32->bf16 transpose through (now free) LDS
  float* scr = (float*)smem + wid * 1088;    // 16 rows x 68
  #pragma unroll
  for (int g = 0; g < 3; ++g) {
    #pragma unroll
    for (int f = 0; f < 4; ++f)
      #pragma unroll
      for (int r = 0; r < 4; ++r)
        scr[(quad * 4 + r) * 68 + f * 16 + mcol] = oT[g][f][r];
    // same-wave LDS RAW: compiler inserts lgkmcnt
    #pragma unroll
    for (int ps = 0; ps < 2; ++ps) {
      const int row = ps * 8 + (lane >> 3), cb = (lane & 7) * 8;
      const floatx4 a = *(const floatx4*)(scr + row * 68 + cb);
      const floatx4 c = *(const floatx4*)(scr + row * 68 + cb + 4);
      int4v pk;
      pk[0] = pk2(a[0], a[1]); pk[1] = pk2(a[2], a[3]);
      pk[2] = pk2(c[0], c[1]); pk[3] = pk2(c[2], c[3]);
      *(int4v*)(opart + ((long)split * NTOK + t0q + g * 16 + row) * 64 + cb) = pk;
    }
  }

  #pragma unroll
  for (int g = 0; g < 3; ++g) {
    float v = lsum[g];
    v += __shfl_xor(v, 16); v += __shfl_xor(v, 32);
    if (lane < 16) lpart[(long)split * NTOK + t0q + g * 16 + lane] = v;
  }
}

// ======================================================================
// k_post: merge split partials -> att; wo-GEMM + residual; LN2; w1-GEMM
// + exact GELU; w2-GEMM + residual; mask; transposed coalesced store.
// ======================================================================
__global__ __launch_bounds__(256) void k_post(
    const unsigned short* __restrict__ opart, const float* __restrict__ lpart,
    const unsigned short* __restrict__ h_bf, const float* __restrict__ maskf,
    const unsigned short* __restrict__ wobf, const float* __restrict__ bo,
    const float* __restrict__ g2, const float* __restrict__ b2,
    const unsigned short* __restrict__ w1bf, const float* __restrict__ bf1,
    const unsigned short* __restrict__ w2bf, const float* __restrict__ bf2,
    float* __restrict__ out)
{
  __shared__ float          h2_lds[32 * 68];
  __shared__ unsigned short att_lds[32 * 72];
  __shared__ unsigned short hn_lds[32 * 72];
  __shared__ unsigned short g_lds[32 * 264];
  __shared__ float          ot_lds[32 * 68];
  __shared__ float          linv[32];
  __shared__ float          st_mu[32], st_rs[32];

  const int tid = threadIdx.x, wid = tid >> 6, lane = tid & 63;
  const int mcol = lane & 15, quad = lane >> 4;
  const int t0 = blockIdx.x * 32;
  const int b = t0 / HW, n0 = t0 % HW;

  if (tid < 32) {
    float l = 0.f;
    #pragma unroll
    for (int s = 0; s < SPLITS; ++s) l += lpart[(long)s * NTOK + t0 + tid];
    linv[tid] = 1.0f / l;
  }

  // phase 1: merge O partials, att (bf16) and h2 prefill (h + bo)
  const int tok = tid >> 3, c8 = (tid & 7) * 8;
  float o[8];
  #pragma unroll
  for (int i = 0; i < 8; ++i) o[i] = 0.f;
  #pragma unroll
  for (int s = 0; s < SPLITS; ++s) {
    const short8 op = *(const short8*)(opart + ((long)s * NTOK + t0 + tok) * 64 + c8);
    #pragma unroll
    for (int i = 0; i < 8; ++i) o[i] += bf2f((unsigned short)op[i]);
  }
  const short8 hb8 = *(const short8*)(h_bf + (long)(t0 + tok) * 64 + c8);
  const floatx4 bo0 = *(const floatx4*)(bo + c8);
  const floatx4 bo1 = *(const floatx4*)(bo + c8 + 4);
  __syncthreads();
  {
    const float sc = linv[tok];
    int4v av;
    av[0] = pk2(o[0]*sc, o[1]*sc); av[1] = pk2(o[2]*sc, o[3]*sc);
    av[2] = pk2(o[4]*sc, o[5]*sc); av[3] = pk2(o[6]*sc, o[7]*sc);
    *(int4v*)(att_lds + tok * 72 + c8) = av;
    floatx4 h20, h21;
    #pragma unroll
    for (int i = 0; i < 4; ++i) {
      h20[i] = bf2f((unsigned short)hb8[i])     + bo0[i];
      h21[i] = bf2f((unsigned short)hb8[i + 4]) + bo1[i];
    }
    *(floatx4*)(h2_lds + tok * 68 + c8)     = h20;
    *(floatx4*)(h2_lds + tok * 68 + c8 + 4) = h21;
  }
  __syncthreads();

  // phase 2: wo-GEMM, D added into h2_lds
  const int Mt = wid & 1, nbase = (wid >> 1) * 2;
  {
    const short8 aA0 = *(const short8*)(att_lds + (Mt * 16 + mcol) * 72 + quad * 8);
    const short8 aA1 = *(const short8*)(att_lds + (Mt * 16 + mcol) * 72 + 32 + quad * 8);
    #pragma unroll
    for (int nt = 0; nt < 2; ++nt) {
      const int nc = (nbase + nt) * 16;
      const short8 b0 = *(const short8*)(wobf + (nc + mcol) * 64 + quad * 8);
      const short8 b1 = *(const short8*)(wobf + (nc + mcol) * 64 + 32 + quad * 8);
      floatx4 d = (floatx4){0.f,0.f,0.f,0.f};
      d = __builtin_amdgcn_mfma_f32_16x16x32_bf16(aA0, b0, d, 0, 0, 0);
      d = __builtin_amdgcn_mfma_f32_16x16x32_bf16(aA1, b1, d, 0, 0, 0);
      #pragma unroll
      for (int r = 0; r < 4; ++r)
        h2_lds[(Mt * 16 + quad * 4 + r) * 68 + nc + mcol] += d[r];
    }
  }
  __syncthreads();

  // phase 3: LN2 stats
  {
    floatx4 v0 = *(const floatx4*)(h2_lds + tok * 68 + c8);
    floatx4 v1 = *(const floatx4*)(h2_lds + tok * 68 + c8 + 4);
    float s1 = (v0[0]+v0[1])+(v0[2]+v0[3]) + (v1[0]+v1[1])+(v1[2]+v1[3]);
    float s2 = (v0[0]*v0[0]+v0[1]*v0[1])+(v0[2]*v0[2]+v0[3]*v0[3])
             + (v1[0]*v1[0]+v1[1]*v1[1])+(v1[2]*v1[2]+v1[3]*v1[3]);
    #pragma unroll
    for (int d = 1; d < 8; d <<= 1) { s1 += __shfl_xor(s1, d); s2 += __shfl_xor(s2, d); }
    if ((tid & 7) == 0) {
      const float mu = s1 * (1.f / 64.f);
      const float var = s2 * (1.f / 64.f) - mu * mu;
      st_mu[tok] = mu; st_rs[tok] = rsqrtf(var + 1e-5f);
    }
  }
  __syncthreads();

  // phase 4: hn (bf16) for w1-GEMM
  {
    const float mu = st_mu[tok], rs = st_rs[tok];
    const floatx4 v0 = *(const floatx4*)(h2_lds + tok * 68 + c8);
    const floatx4 v1 = *(const floatx4*)(h2_lds + tok * 68 + c8 + 4);
    const floatx4 ga = *(const floatx4*)(g2 + c8), gb = *(const floatx4*)(g2 + c8 + 4);
    const floatx4 ba = *(const floatx4*)(b2 + c8), bb = *(const floatx4*)(b2 + c8 + 4);
    float hn[8];
    #pragma unroll
    for (int i = 0; i < 4; ++i) {
      hn[i]     = (v0[i] - mu) * rs * ga[i] + ba[i];
      hn[i + 4] = (v1[i] - mu) * rs * gb[i] + bb[i];
    }
    int4v hv;
    hv[0] = pk2(hn[0], hn[1]); hv[1] = pk2(hn[2], hn[3]);
    hv[2] = pk2(hn[4], hn[5]); hv[3] = pk2(hn[6], hn[7]);
    *(int4v*)(hn_lds + tok * 72 + c8) = hv;
  }
  __syncthreads();

  // phase 5: w1-GEMM + exact GELU -> g_lds (bf16)
  {
    const short8 aA0 = *(const short8*)(hn_lds + (Mt * 16 + mcol) * 72 + quad * 8);
    const short8 aA1 = *(const short8*)(hn_lds + (Mt * 16 + mcol) * 72 + 32 + quad * 8);
    #pragma unroll
    for (int nt = 0; nt < 8; ++nt) {
      const int u0 = ((wid >> 1) * 8 + nt) * 16;
      const short8 b0 = *(const short8*)(w1bf + (u0 + mcol) * 64 + quad * 8);
      const short8 b1 = *(const short8*)(w1bf + (u0 + mcol) * 64 + 32 + quad * 8);
      floatx4 d = (floatx4){0.f,0.f,0.f,0.f};
      d = __builtin_amdgcn_mfma_f32_16x16x32_bf16(aA0, b0, d, 0, 0, 0);
      d = __builtin_amdgcn_mfma_f32_16x16x32_bf16(aA1, b1, d, 0, 0, 0);
      const float bf1v = bf1[u0 + mcol];
      #pragma unroll
      for (int r = 0; r < 4; ++r) {
        const float a = d[r] + bf1v;
        const float gl = 0.5f * a * (1.0f + erff(a * 0.70710678118654752f));
        g_lds[(Mt * 16 + quad * 4 + r) * 264 + u0 + mcol] = f2bf(gl);
      }
    }
  }
  __syncthreads();

  // phase 6: w2-GEMM + residual + mask -> ot_lds
  {
    floatx4 acc[2];
    acc[0] = (floatx4){0.f,0.f,0.f,0.f}; acc[1] = (floatx4){0.f,0.f,0.f,0.f};
    #pragma unroll
    for (int ks = 0; ks < 8; ++ks) {
      const short8 aA = *(const short8*)(g_lds + (Mt * 16 + mcol) * 264 + ks * 32 + quad * 8);
      #pragma unroll
      for (int nt = 0; nt < 2; ++nt) {
        const int nc = (nbase + nt) * 16;
        const short8 bB = *(const short8*)(w2bf + (nc + mcol) * 256 + ks * 32 + quad * 8);
        acc[nt] = __builtin_amdgcn_mfma_f32_16x16x32_bf16(aA, bB, acc[nt], 0, 0, 0);
      }
    }
    #pragma unroll
    for (int nt = 0; nt < 2; ++nt) {
      const int cc = (nbase + nt) * 16 + mcol;
      const float g2v = g2[cc], b2v = b2[cc], bf2v = bf2[cc];
      #pragma unroll
      for (int r = 0; r < 4; ++r) {
        const int tokr = Mt * 16 + quad * 4 + r;
        const float hn = (h2_lds[tokr * 68 + cc] - st_mu[tokr]) * st_rs[tokr] * g2v + b2v;
        const float o  = (hn + acc[nt][r] + bf2v) * maskf[t0 + tokr];
        ot_lds[tokr * 68 + cc] = o;
      }
    }
  }
  __syncthreads();

  // transposed coalesced store: out[b][c][n]
  {
    const int c = tid >> 2, tg = (tid & 3) * 8;
    floatx4 v0, v1;
    #pragma unroll
    for (int i = 0; i < 4; ++i) {
      v0[i] = ot_lds[(tg + i) * 68 + c];
      v1[i] = ot_lds[(tg + 4 + i) * 68 + c];
    }
    float* dst = out + ((long)b * 64 + c) * HW + n0 + tg;
    *(floatx4*)dst = v0;
    *(floatx4*)(dst + 4) = v1;
  }
}

// ======================================================================
extern "C" void kernel_launch(void* const* d_in, const int* in_sizes, int n_in,
                              void* d_out, int out_size, void* d_ws, size_t ws_size,
                              hipStream_t stream) {
  (void)in_sizes; (void)n_in; (void)out_size; (void)ws_size;
  const float* x   = (const float*)d_in[0];
  const int*   msk = (const int*)  d_in[1];
  const float* wq  = (const float*)d_in[2];
  const float* bq  = (const float*)d_in[3];
  const float* wk  = (const float*)d_in[4];
  const float* bk  = (const float*)d_in[5];
  const float* wv  = (const float*)d_in[6];
  const float* bv  = (const float*)d_in[7];
  const float* wo  = (const float*)d_in[8];
  const float* bo  = (const float*)d_in[9];
  const float* g1  = (const float*)d_in[10];
  const float* b1  = (const float*)d_in[11];
  const float* g2  = (const float*)d_in[12];
  const float* b2  = (const float*)d_in[13];
  const float* w1  = (const float*)d_in[14];
  const float* bf1 = (const float*)d_in[15];
  const float* w2  = (const float*)d_in[16];
  const float* bf2 = (const float*)d_in[17];
  float* out = (float*)d_out;

  // workspace layout (bytes), all 16B-aligned; total ~29.0 MB
  char* ws = (char*)d_ws;
  unsigned short* h_bf  = (unsigned short*)(ws + 0);          //  2,359,296
  unsigned short* qg    = (unsigned short*)(ws + 2359296);    //  2,359,296
  unsigned short* ksw   = (unsigned short*)(ws + 4718592);    //  2,359,296 (576 tiles x 4KB)
  unsigned short* vsw   = (unsigned short*)(ws + 7077888);    //  2,359,296
  unsigned short* opart = (unsigned short*)(ws + 9437184);    // 18,874,368 (8 splits, bf16)
  float*          lpart = (float*)(ws + 28311552);            //    589,824
  float*          maskf = (float*)(ws + 28901376);            //     73,728
  unsigned short* wobf  = (unsigned short*)(ws + 28975104);   //      8,192
  unsigned short* w1bf  = (unsigned short*)(ws + 28983296);   //     32,768
  unsigned short* w2bf  = (unsigned short*)(ws + 29016064);   //     32,768

  k_qkv <<<dim3(576), dim3(256), 0, stream>>>(
      x, wq, bq, wk, bk, wv, bv, g1, b1, msk, wo, w1, w2,
      h_bf, qg, ksw, vsw, maskf, wobf, w1bf, w2bf);
  k_attn<<<dim3(96 * SPLITS), dim3(256), 0, stream>>>(qg, ksw, vsw, maskf, opart, lpart);
  k_post<<<dim3(576), dim3(256), 0, stream>>>(
      opart, lpart, h_bf, maskf, wobf, bo, g2, b2, w1bf, bf1, w2bf, bf2, out);
}